// Round 1
// 1491.087 us; speedup vs baseline: 1.1520x; 1.1520x over previous
//
#include <hip/hip_runtime.h>

typedef unsigned short u16;
typedef __attribute__((ext_vector_type(8))) short bf16x8;   // 8 bf16 = 4 VGPRs
typedef __attribute__((ext_vector_type(4))) float f32x4;

// ---- problem constants ----
constexpr int NV = 50257;   // vocab
constexpr int ND = 512;     // hidden
constexpr int NT = 4096;    // seq len
constexpr int NB = 8;       // batch
constexpr int NM = NB * NT; // 32768 tokens
constexpr int NSLOTS = 256;
constexpr int NK = 8;       // lookahead window

__device__ __forceinline__ float b2f(u16 u) { return __uint_as_float(((unsigned)u) << 16); }
__device__ __forceinline__ u16 f2b(float f) {
    unsigned u = __float_as_uint(f);
    u += 0x7FFFu + ((u >> 16) & 1u);   // round-to-nearest-even
    return (u16)(u >> 16);
}

// Dual-dtype element loads. isf32 is wave-uniform (device-detected flag).
__device__ __forceinline__ float ld1(const void* p, size_t i, bool isf32) {
    return isf32 ? ((const float*)p)[i] : b2f(((const u16*)p)[i]);
}
__device__ __forceinline__ float4 ld4(const void* p, size_t i, bool isf32) {
    if (isf32) return *(const float4*)((const float*)p + i);
    ushort4 v = *(const ushort4*)((const u16*)p + i);
    return make_float4(b2f(v.x), b2f(v.y), b2f(v.z), b2f(v.w));
}

// async global->LDS, 16B per lane (dest = wave-uniform base + lane*16)
__device__ __forceinline__ void gll16(const void* g, void* l) {
    __builtin_amdgcn_global_load_lds(
        (const __attribute__((address_space(1))) void*)g,
        (__attribute__((address_space(3))) void*)l, 16, 0, 0);
}

// ============================================================================
// Dtype detection: sample even-indexed u16s of W1 (512*1024 randn*0.02 elems).
// bf16 data -> exponent field in [100,130] for ~100% of samples.
// f32 data  -> even u16s are mantissa halves, exponent ~uniform -> ~12%.
// ============================================================================
__global__ __launch_bounds__(256) void k_detect(const void* w1, int* flag)
{
    __shared__ int red[256];
    const int tid = threadIdx.x;
    const u16* p = (const u16*)w1;
    int good = 0;
    for (int i = 0; i < 16; ++i) {
        u16 v = p[(size_t)(tid * 16 + i) * 2];   // even index
        int e = (v >> 7) & 0xFF;
        good += (e >= 100 && e <= 130) ? 1 : 0;
    }
    red[tid] = good;
    __syncthreads();
    for (int off = 128; off > 0; off >>= 1) {
        if (tid < off) red[tid] += red[tid + off];
        __syncthreads();
    }
    if (tid == 0) *flag = (red[0] < 2048) ? 1 : 0;   // <50% plausible => f32
}

// ============================================================================
// Gather + split: A1 = embed[seq] as bf16 hi/lo row-major [NM][512].
// hi = rne_bf16(x); lo = rne_bf16(x - hi). For bf16 input: hi = x, lo = 0.
// ============================================================================
__global__ __launch_bounds__(256) void k_splitA(const int* __restrict__ seq,
                                                const void* __restrict__ embed,
                                                u16* __restrict__ hi,
                                                u16* __restrict__ lo,
                                                const int* __restrict__ dflag)
{
    const bool isf32 = (*dflag != 0);
    int gid = blockIdx.x * 256 + threadIdx.x;   // one 8-elem chunk per thread
    int m = gid >> 6;
    int kc = (gid & 63) * 8;
    size_t src = (size_t)seq[m] * ND + kc;
    float4 a = ld4(embed, src, isf32);
    float4 b = ld4(embed, src + 4, isf32);
    float v[8] = {a.x, a.y, a.z, a.w, b.x, b.y, b.z, b.w};
    u16 hv[8], lv[8];
#pragma unroll
    for (int i = 0; i < 8; ++i) {
        hv[i] = f2b(v[i]);
        lv[i] = f2b(v[i] - b2f(hv[i]));
    }
    size_t dst = (size_t)m * ND + kc;
    *(ushort4*)&hi[dst]     = make_ushort4(hv[0], hv[1], hv[2], hv[3]);
    *(ushort4*)&hi[dst + 4] = make_ushort4(hv[4], hv[5], hv[6], hv[7]);
    *(ushort4*)&lo[dst]     = make_ushort4(lv[0], lv[1], lv[2], lv[3]);
    *(ushort4*)&lo[dst + 4] = make_ushort4(lv[4], lv[5], lv[6], lv[7]);
}

// ============================================================================
// Transpose + split: src [R][C] (f32 or bf16) -> hiT/loT [C][R] bf16.
// Used for W1 (512x1024 -> [1024][512]) and W2 (1024x512 -> [512][1024]),
// so B-fragments become K-contiguous.
// ============================================================================
__global__ __launch_bounds__(256) void k_splitWT(const void* __restrict__ src,
                                                 u16* __restrict__ hiT,
                                                 u16* __restrict__ loT,
                                                 int R, int C,
                                                 const int* __restrict__ dflag)
{
    const bool isf32 = (*dflag != 0);
    __shared__ float tile[32][33];
    const int tx = threadIdx.x & 31, ty = threadIdx.x >> 5;   // 32 x 8
    const int c0 = blockIdx.x * 32, r0 = blockIdx.y * 32;
#pragma unroll
    for (int k = 0; k < 4; ++k)
        tile[ty + 8 * k][tx] = ld1(src, (size_t)(r0 + ty + 8 * k) * C + c0 + tx, isf32);
    __syncthreads();
#pragma unroll
    for (int k = 0; k < 4; ++k) {
        float v = tile[tx][ty + 8 * k];
        u16 h = f2b(v);
        u16 l = f2b(v - b2f(h));
        size_t o = (size_t)(c0 + ty + 8 * k) * R + r0 + tx;
        hiT[o] = h;
        loT[o] = l;
    }
}

// ============================================================================
// Split-bf16 MFMA GEMM: C[128x128 tile] = A[m][K] @ B^T[n][K] via
// Ah*Bh + Al*Bh + Ah*Bl (3 products ~= f32 precision).
// 256 thr = 4 waves (2x2 quadrants of 64x64), mfma_f32_16x16x32_bf16,
// K-step 32, LDS in fragment order (gather done by per-lane gll sources,
// frag ds_read_b128 at lane*16 -> conflict-free).
// SPLITOUT: relu(acc+bias) -> split -> t1hi/t1lo [m][1024]  (GEMM1)
// else    : acc + bias + embed[seq[m]] -> h f32 [m][512]    (GEMM2)
// ============================================================================
template<int KSTEPS, bool SPLITOUT>
__global__ __launch_bounds__(256) void k_mfma(
    const u16* __restrict__ Ahi, const u16* __restrict__ Alo,
    const u16* __restrict__ Bhi, const u16* __restrict__ Blo,
    const void* __restrict__ bias,
    u16* __restrict__ Chi, u16* __restrict__ Clo,
    float* __restrict__ Cf, const int* __restrict__ seqg,
    const void* __restrict__ embed, int mG0,
    const int* __restrict__ dflag)
{
    constexpr int K = KSTEPS * 32;
    const bool isf32 = (*dflag != 0);
    __shared__ __align__(16) u16 lds[16384];   // [Ahi|Alo|Bhi|Blo] x 4096 u16 (8KB each)
    const int tid = threadIdx.x;
    const int m0 = blockIdx.x * 128;   // chunk-local
    const int n0 = blockIdx.y * 128;
    const int wid = tid >> 6, lane = tid & 63;
    const int wm = wid >> 1, wn = wid & 1;

    // staging: chunk ch = c*256+tid maps to (mt=ch>>6, r=ch&15, g=(ch>>4)&3);
    // LDS chunk index = mt*64 + (r + 16g)  == fragment lane order.
    const int ch0 = tid, ch1 = tid + 256;
    const int ar0 = ((ch0 >> 6) << 4) + (ch0 & 15);
    const int ar1 = ((ch1 >> 6) << 4) + (ch1 & 15);
    const int ag0 = ((ch0 >> 4) & 3) * 8;
    const int ag1 = ((ch1 >> 4) & 3) * 8;
    const u16* pAh0 = Ahi + (size_t)(m0 + ar0) * K + ag0;
    const u16* pAh1 = Ahi + (size_t)(m0 + ar1) * K + ag1;
    const u16* pAl0 = Alo + (size_t)(m0 + ar0) * K + ag0;
    const u16* pAl1 = Alo + (size_t)(m0 + ar1) * K + ag1;
    const u16* pBh0 = Bhi + (size_t)(n0 + ar0) * K + ag0;
    const u16* pBh1 = Bhi + (size_t)(n0 + ar1) * K + ag1;
    const u16* pBl0 = Blo + (size_t)(n0 + ar0) * K + ag0;
    const u16* pBl1 = Blo + (size_t)(n0 + ar1) * K + ag1;

    f32x4 acc[4][4];
#pragma unroll
    for (int i = 0; i < 4; ++i)
#pragma unroll
        for (int j = 0; j < 4; ++j) {
            acc[i][j][0] = 0.f; acc[i][j][1] = 0.f;
            acc[i][j][2] = 0.f; acc[i][j][3] = 0.f;
        }

    u16* dst = lds + tid * 8;
    const u16* fA = lds + wm * 2048 + lane * 8;
    const u16* fB = lds + 8192 + wn * 2048 + lane * 8;

    for (int ks = 0; ks < KSTEPS; ++ks) {
        gll16(pAh0, dst);
        gll16(pAh1, dst + 2048);
        gll16(pAl0, dst + 4096);
        gll16(pAl1, dst + 6144);
        gll16(pBh0, dst + 8192);
        gll16(pBh1, dst + 10240);
        gll16(pBl0, dst + 12288);
        gll16(pBl1, dst + 14336);
        pAh0 += 32; pAh1 += 32; pAl0 += 32; pAl1 += 32;
        pBh0 += 32; pBh1 += 32; pBl0 += 32; pBl1 += 32;
        __syncthreads();   // drains vmcnt: staged data visible
        bf16x8 ah[4], al[4];
#pragma unroll
        for (int i = 0; i < 4; ++i) {
            ah[i] = *(const bf16x8*)(fA + i * 512);
            al[i] = *(const bf16x8*)(fA + 4096 + i * 512);
        }
#pragma unroll
        for (int j = 0; j < 4; ++j) {
            bf16x8 bh = *(const bf16x8*)(fB + j * 512);
            bf16x8 bl = *(const bf16x8*)(fB + 4096 + j * 512);
#pragma unroll
            for (int i = 0; i < 4; ++i)
                acc[i][j] = __builtin_amdgcn_mfma_f32_16x16x32_bf16(ah[i], bh, acc[i][j], 0, 0, 0);
#pragma unroll
            for (int i = 0; i < 4; ++i)
                acc[i][j] = __builtin_amdgcn_mfma_f32_16x16x32_bf16(al[i], bh, acc[i][j], 0, 0, 0);
#pragma unroll
            for (int i = 0; i < 4; ++i)
                acc[i][j] = __builtin_amdgcn_mfma_f32_16x16x32_bf16(ah[i], bl, acc[i][j], 0, 0, 0);
        }
        __syncthreads();   // protect LDS before next stage
    }

    // ---- epilogue. C/D layout: col = lane&15, row = (lane>>4)*4 + reg ----
    const int lr = (lane >> 4) * 4;
    const int lc = lane & 15;
    if (SPLITOUT) {
#pragma unroll
        for (int j = 0; j < 4; ++j) {
            int col = n0 + wn * 64 + j * 16 + lc;
            float bv = ld1(bias, col, isf32);
#pragma unroll
            for (int i = 0; i < 4; ++i) {
                int row = m0 + wm * 64 + i * 16 + lr;
#pragma unroll
                for (int r = 0; r < 4; ++r) {
                    float v = fmaxf(acc[i][j][r] + bv, 0.f);
                    u16 hu = f2b(v);
                    Chi[(size_t)(row + r) * 1024 + col] = hu;
                    Clo[(size_t)(row + r) * 1024 + col] = f2b(v - b2f(hu));
                }
            }
        }
    } else {
        int* sSeq = (int*)lds;   // reuse LDS (main loop ended with barrier)
        if (tid < 128) sSeq[tid] = seqg[mG0 + m0 + tid];
        __syncthreads();
#pragma unroll
        for (int j = 0; j < 4; ++j) {
            int col = n0 + wn * 64 + j * 16 + lc;
            float bv = ld1(bias, col, isf32);
#pragma unroll
            for (int i = 0; i < 4; ++i) {
                int br = wm * 64 + i * 16 + lr;
#pragma unroll
                for (int r = 0; r < 4; ++r) {
                    float v = acc[i][j][r] + bv
                            + ld1(embed, (size_t)sSeq[br + r] * ND + col, isf32);
                    Cf[(size_t)(mG0 + m0 + br + r) * ND + col] = v;
                }
            }
        }
    }
}

// ============================================================================
// In-place LayerNorm over last dim (512), one block per row
// ============================================================================
__global__ __launch_bounds__(256) void k_ln(float* __restrict__ h,
                                            const void* __restrict__ g,
                                            const void* __restrict__ b,
                                            const int* __restrict__ dflag)
{
    const bool isf32 = (*dflag != 0);
    __shared__ float red[256];
    const int tid = threadIdx.x;
    float* p = h + (size_t)blockIdx.x * ND;
    float2 x = *(float2*)(p + tid * 2);
    red[tid] = x.x + x.y;
    __syncthreads();
    for (int off = 128; off > 0; off >>= 1) {
        if (tid < off) red[tid] += red[tid + off];
        __syncthreads();
    }
    float mean = red[0] * (1.f / 512.f);
    __syncthreads();
    float d0 = x.x - mean, d1 = x.y - mean;
    red[tid] = d0 * d0 + d1 * d1;
    __syncthreads();
    for (int off = 128; off > 0; off >>= 1) {
        if (tid < off) red[tid] += red[tid + off];
        __syncthreads();
    }
    float rstd = rsqrtf(red[0] * (1.f / 512.f) + 1e-5f);
    float2 o;
    o.x = d0 * rstd * ld1(g, tid * 2, isf32)     + ld1(b, tid * 2, isf32);
    o.y = d1 * rstd * ld1(g, tid * 2 + 1, isf32) + ld1(b, tid * 2 + 1, isf32);
    *(float2*)(p + tid * 2) = o;
}

// ============================================================================
// Per-token gate partial dots: g1[m]=h[m]·gW[0:512], g2[m]=h[m]·gW[512:1024]
// ============================================================================
__global__ __launch_bounds__(256) void k_g12(const float* __restrict__ h,
                                             const void* __restrict__ gW,
                                             float* __restrict__ g1,
                                             float* __restrict__ g2,
                                             const int* __restrict__ dflag)
{
    const bool isf32 = (*dflag != 0);
    const int lane = threadIdx.x & 63;
    const int m = blockIdx.x * 4 + (threadIdx.x >> 6);
    const float* row = h + (size_t)m * ND;
    const int d = lane * 8;
    float4 h0 = *(const float4*)(row + d);
    float4 h1 = *(const float4*)(row + d + 4);
    float4 wa = ld4(gW, d, isf32);
    float4 wb = ld4(gW, d + 4, isf32);
    float4 va = ld4(gW, 512 + d, isf32);
    float4 vb = ld4(gW, 512 + d + 4, isf32);
    float s1 = h0.x * wa.x + h0.y * wa.y + h0.z * wa.z + h0.w * wa.w
             + h1.x * wb.x + h1.y * wb.y + h1.z * wb.z + h1.w * wb.w;
    float s2 = h0.x * va.x + h0.y * va.y + h0.z * va.z + h0.w * va.w
             + h1.x * vb.x + h1.y * vb.y + h1.z * vb.z + h1.w * vb.w;
#pragma unroll
    for (int off = 32; off > 0; off >>= 1) {
        s1 += __shfl_down(s1, off, 64);
        s2 += __shfl_down(s2, off, 64);
    }
    if (lane == 0) { g1[m] = s1; g2[m] = s2; }
}

// ============================================================================
// Gate logit: g1[m] + mean(g2[m+1 .. m+cnt]), cnt = min(K, T-1-t)
// (sigmoid and gate_b dropped: monotone / constant => same top-k set)
// ============================================================================
__global__ __launch_bounds__(256) void k_gate(const float* __restrict__ g1,
                                              const float* __restrict__ g2,
                                              float* __restrict__ gate)
{
    int m = blockIdx.x * 256 + threadIdx.x;
    int t = m & (NT - 1);
    int cnt = min(NK, NT - 1 - t);
    float s = 0.f;
    for (int i = 1; i <= cnt; ++i) s += g2[m + i];
    float fut = (cnt > 0) ? s / (float)cnt : 0.f;
    gate[m] = g1[m] + fut;
}

// ============================================================================
// Exact top-256 of 4096 per batch via 32-round radix-select on sortable keys.
// Ties at threshold resolved by lowest index (matches jax.lax.top_k set).
// ============================================================================
__global__ __launch_bounds__(256) void k_topk(const float* __restrict__ gate,
                                              int* __restrict__ idxOut)
{
    __shared__ unsigned keys[NT];
    __shared__ int red[256];
    __shared__ int s_cnt;
    const int b = blockIdx.x, tid = threadIdx.x;
    const float* gr = gate + (size_t)b * NT;
    for (int i = tid; i < NT; i += 256) {
        unsigned u = __float_as_uint(gr[i]);
        u = (u & 0x80000000u) ? ~u : (u | 0x80000000u);
        keys[i] = u;
    }
    __syncthreads();
    unsigned sel = 0;
    for (int bit = 31; bit >= 0; --bit) {
        unsigned cand = sel | (1u << bit);
        int c = 0;
        for (int i = tid; i < NT; i += 256) c += (keys[i] >= cand) ? 1 : 0;
        red[tid] = c;
        __syncthreads();
        for (int off = 128; off > 0; off >>= 1) {
            if (tid < off) red[tid] += red[tid + off];
            __syncthreads();
        }
        int total = red[0];
        __syncthreads();
        if (total >= NSLOTS) sel = cand;
    }
    if (tid == 0) s_cnt = 0;
    __syncthreads();
    for (int i = tid; i < NT; i += 256) {
        if (keys[i] > sel) {
            int p = atomicAdd(&s_cnt, 1);
            idxOut[b * NSLOTS + p] = i;
        }
    }
    __syncthreads();
    if (tid == 0) {
        int p = s_cnt;
        for (int i = 0; i < NT && p < NSLOTS; ++i) {
            if (keys[i] == sel) { idxOut[b * NSLOTS + p] = i; ++p; }
        }
    }
}

// ============================================================================
// q[b] = h[b, T-1] @ q_W + q_b   (one block per batch)
// ============================================================================
__global__ __launch_bounds__(256) void k_q(const float* __restrict__ h,
                                           const void* __restrict__ qW,
                                           const void* __restrict__ qb,
                                           float* __restrict__ qo,
                                           const int* __restrict__ dflag)
{
    const bool isf32 = (*dflag != 0);
    const int b = blockIdx.x, tid = threadIdx.x;
    __shared__ float hl[ND];
    const float* row = h + ((size_t)b * NT + (NT - 1)) * ND;
    hl[tid] = row[tid];
    hl[256 + tid] = row[256 + tid];
    __syncthreads();
    for (int j = tid; j < ND; j += 256) {
        float acc = ld1(qb, j, isf32);
        for (int d = 0; d < ND; ++d) acc += hl[d] * ld1(qW, (size_t)d * ND + j, isf32);
        qo[b * ND + j] = acc;
    }
}

// ============================================================================
// scores -> softmax -> ctx  (one block per batch)
// ============================================================================
__global__ __launch_bounds__(256) void k_attn(const float* __restrict__ h,
                                              const float* __restrict__ q,
                                              const int* __restrict__ idx,
                                              float* __restrict__ ctx)
{
    const int b = blockIdx.x, tid = threadIdx.x;
    __shared__ float qv[ND];
    __shared__ float sc[256];
    __shared__ float red[256];
    __shared__ int sidx[256];
    qv[tid] = q[b * ND + tid];
    qv[256 + tid] = q[b * ND + 256 + tid];
    sidx[tid] = idx[b * NSLOTS + tid];
    __syncthreads();
    const float* hb = h + (size_t)b * NT * ND;
    {
        const float* row = hb + (size_t)sidx[tid] * ND;
        float s = 0.f;
        for (int d = 0; d < ND; d += 4) {
            float4 hv = *(const float4*)(row + d);
            float4 qq = *(const float4*)(qv + d);
            s += hv.x * qq.x + hv.y * qq.y + hv.z * qq.z + hv.w * qq.w;
        }
        sc[tid] = s;
        red[tid] = s;
    }
    __syncthreads();
    for (int off = 128; off > 0; off >>= 1) {
        if (tid < off) red[tid] = fmaxf(red[tid], red[tid + off]);
        __syncthreads();
    }
    float mx = red[0];
    __syncthreads();
    float e = expf(sc[tid] - mx);
    red[tid] = e;
    __syncthreads();
    for (int off = 128; off > 0; off >>= 1) {
        if (tid < off) red[tid] += red[tid + off];
        __syncthreads();
    }
    float inv = 1.f / red[0];
    __syncthreads();
    sc[tid] = e * inv;
    __syncthreads();
    for (int d = tid; d < ND; d += 256) {
        float acc = 0.f;
        for (int m = 0; m < NSLOTS; ++m) acc += sc[m] * hb[(size_t)sidx[m] * ND + d];
        ctx[b * ND + d] = acc;
    }
}

// ============================================================================
// out[b][v] = ctx[b] · out_W[:,v] + out_b[v]   (2 columns per thread)
// ============================================================================
__global__ __launch_bounds__(256) void k_out(const float* __restrict__ ctx,
                                             const void* __restrict__ outW,
                                             const void* __restrict__ outb,
                                             void* __restrict__ out,
                                             const int* __restrict__ dflag)
{
    const bool isf32 = (*dflag != 0);
    __shared__ float cs[NB * ND];
    const int tid = threadIdx.x;
    for (int i = tid; i < NB * ND; i += 256) cs[i] = ctx[i];
    __syncthreads();
    int v0 = blockIdx.x * 512 + tid * 2;
    if (v0 >= NV) return;
    bool two = (v0 + 1 < NV);
    float acc0[NB], acc1[NB];
#pragma unroll
    for (int bb = 0; bb < NB; ++bb) { acc0[bb] = 0.f; acc1[bb] = 0.f; }
    for (int d = 0; d < ND; ++d) {
        size_t wb = (size_t)d * NV + v0;
        float w0 = ld1(outW, wb, isf32);
        float w1 = two ? ld1(outW, wb + 1, isf32) : 0.f;
#pragma unroll
        for (int bb = 0; bb < NB; ++bb) {
            float c = cs[bb * ND + d];
            acc0[bb] += c * w0;
            acc1[bb] += c * w1;
        }
    }
    float ob0 = ld1(outb, v0, isf32);
    float ob1 = two ? ld1(outb, v0 + 1, isf32) : 0.f;
#pragma unroll
    for (int bb = 0; bb < NB; ++bb) {
        float r0 = acc0[bb] + ob0;
        float r1 = acc1[bb] + ob1;
        size_t o0 = (size_t)bb * NV + v0;
        if (isf32) {
            ((float*)out)[o0] = r0;
            if (two) ((float*)out)[o0 + 1] = r1;
        } else {
            ((u16*)out)[o0] = f2b(r0);
            if (two) ((u16*)out)[o0 + 1] = f2b(r1);
        }
    }
}

// ============================================================================
extern "C" void kernel_launch(void* const* d_in, const int* in_sizes, int n_in,
                              void* d_out, int out_size, void* d_ws, size_t ws_size,
                              hipStream_t stream)
{
    const int*  seq   = (const int*)d_in[0];
    const void* embed = d_in[1];
    const void* W1    = d_in[2];
    const void* b1    = d_in[3];
    const void* W2    = d_in[4];
    const void* b2v   = d_in[5];
    const void* lng   = d_in[6];
    const void* lnb   = d_in[7];
    const void* gateW = d_in[8];
    // d_in[9] = gate_b (constant shift, irrelevant for top-k ordering)
    const void* qW    = d_in[10];
    const void* qb    = d_in[11];
    const void* outW  = d_in[12];
    const void* outb  = d_in[13];

    // ---- ws layout: flag + small buffers, h (f32), split operand arrays, t1 ----
    float* ws   = (float*)d_ws;
    int*   flag = (int*)ws;                    // ws[0..3] (16B pad)
    float* g1   = ws + 4;                      // NM
    float* g2   = g1 + NM;                     // NM
    float* gate = g2 + NM;                     // NM
    int*   idx  = (int*)(gate + NM);           // NB*NSLOTS
    float* qo   = (float*)(idx + NB * NSLOTS); // NB*ND
    float* ctx  = qo + NB * ND;                // NB*ND
    float* h    = ctx + NB * ND;               // NM*ND f32 (64 MiB)
    u16* A1hi   = (u16*)(h + (size_t)NM * ND); // NM*512 bf16 (32 MiB)
    u16* A1lo   = A1hi + (size_t)NM * ND;      // 32 MiB
    u16* W1thi  = A1lo + (size_t)NM * ND;      // [1024][512] (1 MiB)
    u16* W1tlo  = W1thi + (size_t)1024 * 512;
    u16* W2thi  = W1tlo + (size_t)1024 * 512;  // [512][1024]
    u16* W2tlo  = W2thi + (size_t)1024 * 512;
    u16* t1hi   = W2tlo + (size_t)1024 * 512;  // [MC][1024] bf16 hi

    // ws-adaptive M-chunk for the FFN intermediate (t1 split pair = MC*4096 B).
    // Branch depends only on ws_size: graph-safe.
    const size_t usedB = (size_t)((char*)t1hi - (char*)d_ws);
    int MC;
    if      (ws_size >= usedB + (size_t)32768 * 4096) MC = 32768;
    else if (ws_size >= usedB + (size_t)16384 * 4096) MC = 16384;
    else if (ws_size >= usedB + (size_t)8192  * 4096) MC = 8192;
    else                                              MC = 4096;
    u16* t1lo = t1hi + (size_t)MC * 1024;

    k_detect<<<1, 256, 0, stream>>>(W1, flag);
    k_splitA<<<NM / 4, 256, 0, stream>>>(seq, embed, A1hi, A1lo, flag);
    k_splitWT<<<dim3(32, 16), 256, 0, stream>>>(W1, W1thi, W1tlo, 512, 1024, flag);
    k_splitWT<<<dim3(16, 32), 256, 0, stream>>>(W2, W2thi, W2tlo, 1024, 512, flag);

    for (int m0g = 0; m0g < NM; m0g += MC) {
        // GEMM1: t1 = relu(A1 @ W1 + b1), split-bf16 output
        k_mfma<16, true><<<dim3(MC / 128, 8), 256, 0, stream>>>(
            A1hi + (size_t)m0g * ND, A1lo + (size_t)m0g * ND,
            W1thi, W1tlo, b1,
            t1hi, t1lo,
            nullptr, nullptr, nullptr, 0, flag);
        // GEMM2: h = t1 @ W2 + b2 + embed[seq] (exact f32 residual)
        k_mfma<32, false><<<dim3(MC / 128, 4), 256, 0, stream>>>(
            t1hi, t1lo,
            W2thi, W2tlo, b2v,
            nullptr, nullptr,
            h, seq, embed, m0g, flag);
    }

    k_ln<<<NM, 256, 0, stream>>>(h, lng, lnb, flag);
    k_g12<<<NM / 4, 256, 0, stream>>>(h, gateW, g1, g2, flag);
    k_gate<<<NM / 256, 256, 0, stream>>>(g1, g2, gate);
    k_topk<<<NB, 256, 0, stream>>>(gate, idx);
    k_q<<<NB, 256, 0, stream>>>(h, qW, qb, qo, flag);
    k_attn<<<NB, 256, 0, stream>>>(h, qo, idx, ctx);
    k_out<<<(NV + 511) / 512, 256, 0, stream>>>(ctx, outW, outb, d_out, flag);
}

// Round 2
// 1024.099 us; speedup vs baseline: 1.6773x; 1.4560x over previous
//
#include <hip/hip_runtime.h>

typedef unsigned short u16;
typedef __attribute__((ext_vector_type(8))) short bf16x8;   // 8 bf16 = 4 VGPRs
typedef __attribute__((ext_vector_type(4))) float f32x4;

// ---- problem constants ----
constexpr int NV = 50257;   // vocab
constexpr int ND = 512;     // hidden
constexpr int NT = 4096;    // seq len
constexpr int NB = 8;       // batch
constexpr int NM = NB * NT; // 32768 tokens
constexpr int NSLOTS = 256;
constexpr int NK = 8;       // lookahead window

__device__ __forceinline__ float b2f(u16 u) { return __uint_as_float(((unsigned)u) << 16); }
__device__ __forceinline__ u16 f2b(float f) {
    unsigned u = __float_as_uint(f);
    u += 0x7FFFu + ((u >> 16) & 1u);   // round-to-nearest-even
    return (u16)(u >> 16);
}

// Dual-dtype element loads. isf32 is wave-uniform (device-detected flag).
__device__ __forceinline__ float ld1(const void* p, size_t i, bool isf32) {
    return isf32 ? ((const float*)p)[i] : b2f(((const u16*)p)[i]);
}
__device__ __forceinline__ float4 ld4(const void* p, size_t i, bool isf32) {
    if (isf32) return *(const float4*)((const float*)p + i);
    ushort4 v = *(const ushort4*)((const u16*)p + i);
    return make_float4(b2f(v.x), b2f(v.y), b2f(v.z), b2f(v.w));
}

// async global->LDS, 16B per lane (dest = wave-uniform base + lane*16)
__device__ __forceinline__ void gll16(const void* g, void* l) {
    __builtin_amdgcn_global_load_lds(
        (const __attribute__((address_space(1))) void*)g,
        (__attribute__((address_space(3))) void*)l, 16, 0, 0);
}

// ============================================================================
// Dtype detection: sample even-indexed u16s of W1 (512*1024 randn*0.02 elems).
// bf16 data -> exponent field in [100,130] for ~100% of samples.
// f32 data  -> even u16s are mantissa halves, exponent ~uniform -> ~12%.
// ============================================================================
__global__ __launch_bounds__(256) void k_detect(const void* w1, int* flag)
{
    __shared__ int red[256];
    const int tid = threadIdx.x;
    const u16* p = (const u16*)w1;
    int good = 0;
    for (int i = 0; i < 16; ++i) {
        u16 v = p[(size_t)(tid * 16 + i) * 2];   // even index
        int e = (v >> 7) & 0xFF;
        good += (e >= 100 && e <= 130) ? 1 : 0;
    }
    red[tid] = good;
    __syncthreads();
    for (int off = 128; off > 0; off >>= 1) {
        if (tid < off) red[tid] += red[tid + off];
        __syncthreads();
    }
    if (tid == 0) *flag = (red[0] < 2048) ? 1 : 0;   // <50% plausible => f32
}

// ============================================================================
// Gather + split: A1 = embed[seq] as bf16 hi/lo row-major [NM][512].
// ============================================================================
__global__ __launch_bounds__(256) void k_splitA(const int* __restrict__ seq,
                                                const void* __restrict__ embed,
                                                u16* __restrict__ hi,
                                                u16* __restrict__ lo,
                                                const int* __restrict__ dflag)
{
    const bool isf32 = (*dflag != 0);
    int gid = blockIdx.x * 256 + threadIdx.x;   // one 8-elem chunk per thread
    int m = gid >> 6;
    int kc = (gid & 63) * 8;
    size_t src = (size_t)seq[m] * ND + kc;
    float4 a = ld4(embed, src, isf32);
    float4 b = ld4(embed, src + 4, isf32);
    float v[8] = {a.x, a.y, a.z, a.w, b.x, b.y, b.z, b.w};
    u16 hv[8], lv[8];
#pragma unroll
    for (int i = 0; i < 8; ++i) {
        hv[i] = f2b(v[i]);
        lv[i] = f2b(v[i] - b2f(hv[i]));
    }
    size_t dst = (size_t)m * ND + kc;
    *(ushort4*)&hi[dst]     = make_ushort4(hv[0], hv[1], hv[2], hv[3]);
    *(ushort4*)&hi[dst + 4] = make_ushort4(hv[4], hv[5], hv[6], hv[7]);
    *(ushort4*)&lo[dst]     = make_ushort4(lv[0], lv[1], lv[2], lv[3]);
    *(ushort4*)&lo[dst + 4] = make_ushort4(lv[4], lv[5], lv[6], lv[7]);
}

// ============================================================================
// Transpose + split: src [R][C] (f32 or bf16) -> hiT/loT [C][R] bf16.
// ============================================================================
__global__ __launch_bounds__(256) void k_splitWT(const void* __restrict__ src,
                                                 u16* __restrict__ hiT,
                                                 u16* __restrict__ loT,
                                                 int R, int C,
                                                 const int* __restrict__ dflag)
{
    const bool isf32 = (*dflag != 0);
    __shared__ float tile[32][33];
    const int tx = threadIdx.x & 31, ty = threadIdx.x >> 5;   // 32 x 8
    const int c0 = blockIdx.x * 32, r0 = blockIdx.y * 32;
#pragma unroll
    for (int k = 0; k < 4; ++k)
        tile[ty + 8 * k][tx] = ld1(src, (size_t)(r0 + ty + 8 * k) * C + c0 + tx, isf32);
    __syncthreads();
#pragma unroll
    for (int k = 0; k < 4; ++k) {
        float v = tile[tx][ty + 8 * k];
        u16 h = f2b(v);
        u16 l = f2b(v - b2f(h));
        size_t o = (size_t)(c0 + ty + 8 * k) * R + r0 + tx;
        hiT[o] = h;
        loT[o] = l;
    }
}

// ============================================================================
// Split-bf16 MFMA GEMM, 2-phase double-buffered pipeline.
// C[128x128] = A[m][K] @ B^T[n][K] via Ah*Bh + Al*Bh + Ah*Bl.
// 256 thr = 4 waves (2x2 quadrants of 64x64), mfma_f32_16x16x32_bf16,
// K-step 32, LDS fragment order, stage(t+1) issued before compute(t),
// single __syncthreads (vmcnt+lgkm drain + barrier) per K-step.
// 1-D grid with bijective XCD swizzle; N-tile is the fast dimension so each
// XCD keeps its A-panels L2-resident across all N-tiles.
// ============================================================================
template<int KSTEPS, int NTILES, bool SPLITOUT>
__global__ __launch_bounds__(256) void k_mfma(
    const u16* __restrict__ Ahi, const u16* __restrict__ Alo,
    const u16* __restrict__ Bhi, const u16* __restrict__ Blo,
    const void* __restrict__ bias,
    u16* __restrict__ Chi, u16* __restrict__ Clo,
    float* __restrict__ Cf, const int* __restrict__ seqg,
    const void* __restrict__ embed, int mG0,
    const int* __restrict__ dflag)
{
    constexpr int K = KSTEPS * 32;
    const bool isf32 = (*dflag != 0);
    __shared__ __align__(16) u16 lds[2][16384];  // dbuf x [Ahi|Alo|Bhi|Blo] (8KB each)
    const int tid = threadIdx.x;

    // bijective XCD swizzle (gridDim.x % 8 == 0): XCD k gets contiguous wg range
    const int lin = blockIdx.x;
    const int qx = gridDim.x >> 3;
    const int wg = (lin & 7) * qx + (lin >> 3);
    const int m0 = (wg / NTILES) * 128;   // chunk-local
    const int n0 = (wg % NTILES) * 128;

    const int wid = tid >> 6, lane = tid & 63;
    const int wm = wid >> 1, wn = wid & 1;

    // staging: chunk ch = c*256+tid maps to (mt=ch>>6, r=ch&15, g=(ch>>4)&3);
    // LDS chunk index = mt*64 + (r + 16g)  == fragment lane order.
    const int ch0 = tid, ch1 = tid + 256;
    const int ar0 = ((ch0 >> 6) << 4) + (ch0 & 15);
    const int ar1 = ((ch1 >> 6) << 4) + (ch1 & 15);
    const int ag0 = ((ch0 >> 4) & 3) * 8;
    const int ag1 = ((ch1 >> 4) & 3) * 8;
    const u16* pAh0 = Ahi + (size_t)(m0 + ar0) * K + ag0;
    const u16* pAh1 = Ahi + (size_t)(m0 + ar1) * K + ag1;
    const u16* pAl0 = Alo + (size_t)(m0 + ar0) * K + ag0;
    const u16* pAl1 = Alo + (size_t)(m0 + ar1) * K + ag1;
    const u16* pBh0 = Bhi + (size_t)(n0 + ar0) * K + ag0;
    const u16* pBh1 = Bhi + (size_t)(n0 + ar1) * K + ag1;
    const u16* pBl0 = Blo + (size_t)(n0 + ar0) * K + ag0;
    const u16* pBl1 = Blo + (size_t)(n0 + ar1) * K + ag1;

    f32x4 acc[4][4];
#pragma unroll
    for (int i = 0; i < 4; ++i)
#pragma unroll
        for (int j = 0; j < 4; ++j) {
            acc[i][j][0] = 0.f; acc[i][j][1] = 0.f;
            acc[i][j][2] = 0.f; acc[i][j][3] = 0.f;
        }

    // prologue: stage K-step 0 into buf 0
    {
        u16* d = &lds[0][tid * 8];
        gll16(pAh0, d);
        gll16(pAh1, d + 2048);
        gll16(pAl0, d + 4096);
        gll16(pAl1, d + 6144);
        gll16(pBh0, d + 8192);
        gll16(pBh1, d + 10240);
        gll16(pBl0, d + 12288);
        gll16(pBl1, d + 14336);
    }
    __syncthreads();

    int cur = 0;
    for (int ks = 0; ks < KSTEPS; ++ks) {
        if (ks + 1 < KSTEPS) {
            // issue next tile's loads early: latency hides under compute
            const int o = (ks + 1) * 32;
            u16* d = &lds[cur ^ 1][tid * 8];
            gll16(pAh0 + o, d);
            gll16(pAh1 + o, d + 2048);
            gll16(pAl0 + o, d + 4096);
            gll16(pAl1 + o, d + 6144);
            gll16(pBh0 + o, d + 8192);
            gll16(pBh1 + o, d + 10240);
            gll16(pBl0 + o, d + 12288);
            gll16(pBl1 + o, d + 14336);
            __builtin_amdgcn_sched_barrier(0);   // keep issue before ds_reads
        }
        const u16* fA = &lds[cur][wm * 2048 + lane * 8];
        const u16* fB = &lds[cur][8192 + wn * 2048 + lane * 8];
        bf16x8 ah[4], al[4];
#pragma unroll
        for (int i = 0; i < 4; ++i) {
            ah[i] = *(const bf16x8*)(fA + i * 512);
            al[i] = *(const bf16x8*)(fA + 4096 + i * 512);
        }
#pragma unroll
        for (int j = 0; j < 4; ++j) {
            bf16x8 bh = *(const bf16x8*)(fB + j * 512);
            bf16x8 bl = *(const bf16x8*)(fB + 4096 + j * 512);
#pragma unroll
            for (int i = 0; i < 4; ++i)
                acc[i][j] = __builtin_amdgcn_mfma_f32_16x16x32_bf16(ah[i], bh, acc[i][j], 0, 0, 0);
#pragma unroll
            for (int i = 0; i < 4; ++i)
                acc[i][j] = __builtin_amdgcn_mfma_f32_16x16x32_bf16(al[i], bh, acc[i][j], 0, 0, 0);
#pragma unroll
            for (int i = 0; i < 4; ++i)
                acc[i][j] = __builtin_amdgcn_mfma_f32_16x16x32_bf16(ah[i], bl, acc[i][j], 0, 0, 0);
        }
        __syncthreads();   // drains next-tile vmcnt (hidden) + protects LDS
        cur ^= 1;
    }

    // ---- epilogue. C/D layout: col = lane&15, row = (lane>>4)*4 + reg ----
    const int lr = (lane >> 4) * 4;
    const int lc = lane & 15;
    if (SPLITOUT) {
#pragma unroll
        for (int j = 0; j < 4; ++j) {
            int col = n0 + wn * 64 + j * 16 + lc;
            float bv = ld1(bias, col, isf32);
#pragma unroll
            for (int i = 0; i < 4; ++i) {
                int row = m0 + wm * 64 + i * 16 + lr;
#pragma unroll
                for (int r = 0; r < 4; ++r) {
                    float v = fmaxf(acc[i][j][r] + bv, 0.f);
                    u16 hu = f2b(v);
                    Chi[(size_t)(row + r) * 1024 + col] = hu;
                    Clo[(size_t)(row + r) * 1024 + col] = f2b(v - b2f(hu));
                }
            }
        }
    } else {
        int* sSeq = (int*)&lds[0][0];   // reuse LDS (loop ended with barrier)
        if (tid < 128) sSeq[tid] = seqg[mG0 + m0 + tid];
        __syncthreads();
#pragma unroll
        for (int j = 0; j < 4; ++j) {
            int col = n0 + wn * 64 + j * 16 + lc;
            float bv = ld1(bias, col, isf32);
#pragma unroll
            for (int i = 0; i < 4; ++i) {
                int br = wm * 64 + i * 16 + lr;
#pragma unroll
                for (int r = 0; r < 4; ++r) {
                    float v = acc[i][j][r] + bv
                            + ld1(embed, (size_t)sSeq[br + r] * ND + col, isf32);
                    Cf[(size_t)(mG0 + m0 + br + r) * ND + col] = v;
                }
            }
        }
    }
}

// ============================================================================
// Fused LayerNorm + gate partial dots, one wave per row, barrier-free.
// h[m] <- LN(h[m]); g1[m] = LN·gW[0:512]; g2[m] = LN·gW[512:1024]
// ============================================================================
__global__ __launch_bounds__(256) void k_lng(float* __restrict__ h,
                                             const void* __restrict__ lg,
                                             const void* __restrict__ lb,
                                             const void* __restrict__ gW,
                                             float* __restrict__ g1,
                                             float* __restrict__ g2,
                                             const int* __restrict__ dflag)
{
    const bool isf32 = (*dflag != 0);
    const int lane = threadIdx.x & 63;
    const int m = blockIdx.x * 4 + (threadIdx.x >> 6);
    float* row = h + (size_t)m * ND;
    const int d = lane * 8;
    float4 x0 = *(float4*)(row + d);
    float4 x1 = *(float4*)(row + d + 4);
    float s = x0.x + x0.y + x0.z + x0.w + x1.x + x1.y + x1.z + x1.w;
#pragma unroll
    for (int off = 32; off > 0; off >>= 1) s += __shfl_xor(s, off, 64);
    float mean = s * (1.f / 512.f);
    float d0 = x0.x - mean, d1 = x0.y - mean, d2 = x0.z - mean, d3 = x0.w - mean;
    float d4 = x1.x - mean, d5 = x1.y - mean, d6 = x1.z - mean, d7 = x1.w - mean;
    float vs = d0 * d0 + d1 * d1 + d2 * d2 + d3 * d3
             + d4 * d4 + d5 * d5 + d6 * d6 + d7 * d7;
#pragma unroll
    for (int off = 32; off > 0; off >>= 1) vs += __shfl_xor(vs, off, 64);
    float rstd = rsqrtf(vs * (1.f / 512.f) + 1e-5f);
    float4 ga = ld4(lg, d, isf32), gb = ld4(lg, d + 4, isf32);
    float4 ba = ld4(lb, d, isf32), bb = ld4(lb, d + 4, isf32);
    float o0 = d0 * rstd * ga.x + ba.x;
    float o1 = d1 * rstd * ga.y + ba.y;
    float o2 = d2 * rstd * ga.z + ba.z;
    float o3 = d3 * rstd * ga.w + ba.w;
    float o4 = d4 * rstd * gb.x + bb.x;
    float o5 = d5 * rstd * gb.y + bb.y;
    float o6 = d6 * rstd * gb.z + bb.z;
    float o7 = d7 * rstd * gb.w + bb.w;
    *(float4*)(row + d)     = make_float4(o0, o1, o2, o3);
    *(float4*)(row + d + 4) = make_float4(o4, o5, o6, o7);
    float4 wa = ld4(gW, d, isf32), wb = ld4(gW, d + 4, isf32);
    float4 va = ld4(gW, 512 + d, isf32), vb = ld4(gW, 512 + d + 4, isf32);
    float s1 = o0 * wa.x + o1 * wa.y + o2 * wa.z + o3 * wa.w
             + o4 * wb.x + o5 * wb.y + o6 * wb.z + o7 * wb.w;
    float s2 = o0 * va.x + o1 * va.y + o2 * va.z + o3 * va.w
             + o4 * vb.x + o5 * vb.y + o6 * vb.z + o7 * vb.w;
#pragma unroll
    for (int off = 32; off > 0; off >>= 1) {
        s1 += __shfl_down(s1, off, 64);
        s2 += __shfl_down(s2, off, 64);
    }
    if (lane == 0) { g1[m] = s1; g2[m] = s2; }
}

// ============================================================================
// Gate logit: g1[m] + mean(g2[m+1 .. m+cnt]), cnt = min(K, T-1-t)
// ============================================================================
__global__ __launch_bounds__(256) void k_gate(const float* __restrict__ g1,
                                              const float* __restrict__ g2,
                                              float* __restrict__ gate)
{
    int m = blockIdx.x * 256 + threadIdx.x;
    int t = m & (NT - 1);
    int cnt = min(NK, NT - 1 - t);
    float s = 0.f;
    for (int i = 1; i <= cnt; ++i) s += g2[m + i];
    float fut = (cnt > 0) ? s / (float)cnt : 0.f;
    gate[m] = g1[m] + fut;
}

// ============================================================================
// Exact top-256 of 4096 per batch via 32-round radix-select on sortable keys.
// Downstream (softmax + weighted sum) is permutation-invariant, so only the
// SET matters; ties at threshold resolved by lowest index (rare slow path).
// ============================================================================
__global__ __launch_bounds__(256) void k_topk(const float* __restrict__ gate,
                                              int* __restrict__ idxOut)
{
    __shared__ unsigned keys[NT];
    __shared__ int red[4];
    __shared__ int s_cnt;
    const int b = blockIdx.x, tid = threadIdx.x;
    const int lane = tid & 63, wv = tid >> 6;
    const float* gr = gate + (size_t)b * NT;
    for (int i = tid; i < NT; i += 256) {
        unsigned u = __float_as_uint(gr[i]);
        u = (u & 0x80000000u) ? ~u : (u | 0x80000000u);
        keys[i] = u;
    }
    __syncthreads();
    unsigned sel = 0;
    for (int bit = 31; bit >= 0; --bit) {
        unsigned cand = sel | (1u << bit);
        int c = 0;
        for (int i = tid; i < NT; i += 256) c += (keys[i] >= cand) ? 1 : 0;
#pragma unroll
        for (int off = 32; off > 0; off >>= 1) c += __shfl_down(c, off, 64);
        if (lane == 0) red[wv] = c;
        __syncthreads();
        int total = red[0] + red[1] + red[2] + red[3];
        __syncthreads();
        if (total >= NSLOTS) sel = cand;
    }
    if (tid == 0) s_cnt = 0;
    __syncthreads();
    for (int i = tid; i < NT; i += 256) {
        if (keys[i] > sel) {
            int p = atomicAdd(&s_cnt, 1);
            idxOut[b * NSLOTS + p] = i;
        }
    }
    __syncthreads();
    const int base = s_cnt;
    int tc = 0;
    for (int i = tid; i < NT; i += 256) tc += (keys[i] == sel) ? 1 : 0;
#pragma unroll
    for (int off = 32; off > 0; off >>= 1) tc += __shfl_down(tc, off, 64);
    if (lane == 0) red[wv] = tc;
    __syncthreads();
    int tcnt = red[0] + red[1] + red[2] + red[3];
    int need = NSLOTS - base;
    if (tcnt == need) {
        for (int i = tid; i < NT; i += 256) {
            if (keys[i] == sel) {
                int p = atomicAdd(&s_cnt, 1);
                idxOut[b * NSLOTS + p] = i;
            }
        }
    } else if (tid == 0) {   // rare: more ties than slots -> lowest indices
        int p = base;
        for (int i = 0; i < NT && p < NSLOTS; ++i)
            if (keys[i] == sel) { idxOut[b * NSLOTS + p] = i; ++p; }
    }
}

// ============================================================================
// q[b] = h[b, T-1] @ q_W + q_b   (one block per batch)
// ============================================================================
__global__ __launch_bounds__(256) void k_q(const float* __restrict__ h,
                                           const void* __restrict__ qW,
                                           const void* __restrict__ qb,
                                           float* __restrict__ qo,
                                           const int* __restrict__ dflag)
{
    const bool isf32 = (*dflag != 0);
    const int b = blockIdx.x, tid = threadIdx.x;
    __shared__ float hl[ND];
    const float* row = h + ((size_t)b * NT + (NT - 1)) * ND;
    hl[tid] = row[tid];
    hl[256 + tid] = row[256 + tid];
    __syncthreads();
    for (int j = tid; j < ND; j += 256) {
        float acc = ld1(qb, j, isf32);
        for (int d = 0; d < ND; ++d) acc += hl[d] * ld1(qW, (size_t)d * ND + j, isf32);
        qo[b * ND + j] = acc;
    }
}

// ============================================================================
// scores -> softmax -> ctx  (one block per batch)
// ============================================================================
__global__ __launch_bounds__(256) void k_attn(const float* __restrict__ h,
                                              const float* __restrict__ q,
                                              const int* __restrict__ idx,
                                              float* __restrict__ ctx)
{
    const int b = blockIdx.x, tid = threadIdx.x;
    __shared__ float qv[ND];
    __shared__ float sc[256];
    __shared__ float red[256];
    __shared__ int sidx[256];
    qv[tid] = q[b * ND + tid];
    qv[256 + tid] = q[b * ND + 256 + tid];
    sidx[tid] = idx[b * NSLOTS + tid];
    __syncthreads();
    const float* hb = h + (size_t)b * NT * ND;
    {
        const float* row = hb + (size_t)sidx[tid] * ND;
        float s = 0.f;
        for (int d = 0; d < ND; d += 4) {
            float4 hv = *(const float4*)(row + d);
            float4 qq = *(const float4*)(qv + d);
            s += hv.x * qq.x + hv.y * qq.y + hv.z * qq.z + hv.w * qq.w;
        }
        sc[tid] = s;
        red[tid] = s;
    }
    __syncthreads();
    for (int off = 128; off > 0; off >>= 1) {
        if (tid < off) red[tid] = fmaxf(red[tid], red[tid + off]);
        __syncthreads();
    }
    float mx = red[0];
    __syncthreads();
    float e = expf(sc[tid] - mx);
    red[tid] = e;
    __syncthreads();
    for (int off = 128; off > 0; off >>= 1) {
        if (tid < off) red[tid] += red[tid + off];
        __syncthreads();
    }
    float inv = 1.f / red[0];
    __syncthreads();
    sc[tid] = e * inv;
    __syncthreads();
    for (int d = tid; d < ND; d += 256) {
        float acc = 0.f;
        for (int m = 0; m < NSLOTS; ++m) acc += sc[m] * hb[(size_t)sidx[m] * ND + d];
        ctx[b * ND + d] = acc;
    }
}

// ============================================================================
// out[b][v] = ctx[b] · out_W[:,v] + out_b[v]   (2 columns per thread)
// ============================================================================
__global__ __launch_bounds__(256) void k_out(const float* __restrict__ ctx,
                                             const void* __restrict__ outW,
                                             const void* __restrict__ outb,
                                             void* __restrict__ out,
                                             const int* __restrict__ dflag)
{
    const bool isf32 = (*dflag != 0);
    __shared__ float cs[NB * ND];
    const int tid = threadIdx.x;
    for (int i = tid; i < NB * ND; i += 256) cs[i] = ctx[i];
    __syncthreads();
    int v0 = blockIdx.x * 512 + tid * 2;
    if (v0 >= NV) return;
    bool two = (v0 + 1 < NV);
    float acc0[NB], acc1[NB];
#pragma unroll
    for (int bb = 0; bb < NB; ++bb) { acc0[bb] = 0.f; acc1[bb] = 0.f; }
    for (int d = 0; d < ND; ++d) {
        size_t wb = (size_t)d * NV + v0;
        float w0 = ld1(outW, wb, isf32);
        float w1 = two ? ld1(outW, wb + 1, isf32) : 0.f;
#pragma unroll
        for (int bb = 0; bb < NB; ++bb) {
            float c = cs[bb * ND + d];
            acc0[bb] += c * w0;
            acc1[bb] += c * w1;
        }
    }
    float ob0 = ld1(outb, v0, isf32);
    float ob1 = two ? ld1(outb, v0 + 1, isf32) : 0.f;
#pragma unroll
    for (int bb = 0; bb < NB; ++bb) {
        float r0 = acc0[bb] + ob0;
        float r1 = acc1[bb] + ob1;
        size_t o0 = (size_t)bb * NV + v0;
        if (isf32) {
            ((float*)out)[o0] = r0;
            if (two) ((float*)out)[o0 + 1] = r1;
        } else {
            ((u16*)out)[o0] = f2b(r0);
            if (two) ((u16*)out)[o0 + 1] = f2b(r1);
        }
    }
}

// ============================================================================
extern "C" void kernel_launch(void* const* d_in, const int* in_sizes, int n_in,
                              void* d_out, int out_size, void* d_ws, size_t ws_size,
                              hipStream_t stream)
{
    const int*  seq   = (const int*)d_in[0];
    const void* embed = d_in[1];
    const void* W1    = d_in[2];
    const void* b1    = d_in[3];
    const void* W2    = d_in[4];
    const void* b2v   = d_in[5];
    const void* lng   = d_in[6];
    const void* lnb   = d_in[7];
    const void* gateW = d_in[8];
    // d_in[9] = gate_b (constant shift, irrelevant for top-k ordering)
    const void* qW    = d_in[10];
    const void* qb    = d_in[11];
    const void* outW  = d_in[12];
    const void* outb  = d_in[13];

    // ---- ws layout: flag + small buffers, h (f32), split operand arrays, t1 ----
    float* ws   = (float*)d_ws;
    int*   flag = (int*)ws;                    // ws[0..3] (16B pad)
    float* g1   = ws + 4;                      // NM
    float* g2   = g1 + NM;                     // NM
    float* gate = g2 + NM;                     // NM
    int*   idx  = (int*)(gate + NM);           // NB*NSLOTS
    float* qo   = (float*)(idx + NB * NSLOTS); // NB*ND
    float* ctx  = qo + NB * ND;                // NB*ND
    float* h    = ctx + NB * ND;               // NM*ND f32 (64 MiB)
    u16* A1hi   = (u16*)(h + (size_t)NM * ND); // NM*512 bf16 (32 MiB)
    u16* A1lo   = A1hi + (size_t)NM * ND;      // 32 MiB
    u16* W1thi  = A1lo + (size_t)NM * ND;      // [1024][512] (1 MiB)
    u16* W1tlo  = W1thi + (size_t)1024 * 512;
    u16* W2thi  = W1tlo + (size_t)1024 * 512;  // [512][1024]
    u16* W2tlo  = W2thi + (size_t)1024 * 512;
    u16* t1hi   = W2tlo + (size_t)1024 * 512;  // [MC][1024] bf16 hi

    // ws-adaptive M-chunk for the FFN intermediate (t1 split pair = MC*4096 B).
    // Branch depends only on ws_size: graph-safe.
    const size_t usedB = (size_t)((char*)t1hi - (char*)d_ws);
    int MC;
    if      (ws_size >= usedB + (size_t)32768 * 4096) MC = 32768;
    else if (ws_size >= usedB + (size_t)16384 * 4096) MC = 16384;
    else if (ws_size >= usedB + (size_t)8192  * 4096) MC = 8192;
    else                                              MC = 4096;
    u16* t1lo = t1hi + (size_t)MC * 1024;

    k_detect<<<1, 256, 0, stream>>>(W1, flag);
    k_splitA<<<NM / 4, 256, 0, stream>>>(seq, embed, A1hi, A1lo, flag);
    k_splitWT<<<dim3(32, 16), 256, 0, stream>>>(W1, W1thi, W1tlo, 512, 1024, flag);
    k_splitWT<<<dim3(16, 32), 256, 0, stream>>>(W2, W2thi, W2tlo, 1024, 512, flag);

    for (int m0g = 0; m0g < NM; m0g += MC) {
        // GEMM1: t1 = relu(A1 @ W1 + b1), split-bf16 output  (grid = MC/128 * 8)
        k_mfma<16, 8, true><<<(MC / 128) * 8, 256, 0, stream>>>(
            A1hi + (size_t)m0g * ND, A1lo + (size_t)m0g * ND,
            W1thi, W1tlo, b1,
            t1hi, t1lo,
            nullptr, nullptr, nullptr, 0, flag);
        // GEMM2: h = t1 @ W2 + b2 + embed[seq] (exact f32 residual)
        k_mfma<32, 4, false><<<(MC / 128) * 4, 256, 0, stream>>>(
            t1hi, t1lo,
            W2thi, W2tlo, b2v,
            nullptr, nullptr,
            h, seq, embed, m0g, flag);
    }

    k_lng<<<NM / 4, 256, 0, stream>>>(h, lng, lnb, gateW, g1, g2, flag);
    k_gate<<<NM / 256, 256, 0, stream>>>(g1, g2, gate);
    k_topk<<<NB, 256, 0, stream>>>(gate, idx);
    k_q<<<NB, 256, 0, stream>>>(h, qW, qb, qo, flag);
    k_attn<<<NB, 256, 0, stream>>>(h, qo, idx, ctx);
    k_out<<<(NV + 511) / 512, 256, 0, stream>>>(ctx, outW, outb, d_out, flag);
}

// Round 3
// 930.414 us; speedup vs baseline: 1.8462x; 1.1007x over previous
//
#include <hip/hip_runtime.h>

typedef unsigned short u16;
typedef __attribute__((ext_vector_type(8))) short bf16x8;   // 8 bf16 = 4 VGPRs
typedef __attribute__((ext_vector_type(4))) float f32x4;

// ---- problem constants ----
constexpr int NV = 50257;   // vocab
constexpr int ND = 512;     // hidden
constexpr int NT = 4096;    // seq len
constexpr int NB = 8;       // batch
constexpr int NM = NB * NT; // 32768 tokens
constexpr int NSLOTS = 256;
constexpr int NK = 8;       // lookahead window

__device__ __forceinline__ float b2f(u16 u) { return __uint_as_float(((unsigned)u) << 16); }
__device__ __forceinline__ u16 f2b(float f) {
    unsigned u = __float_as_uint(f);
    u += 0x7FFFu + ((u >> 16) & 1u);   // round-to-nearest-even
    return (u16)(u >> 16);
}

// Dual-dtype element loads. isf32 is wave-uniform (device-detected flag).
__device__ __forceinline__ float ld1(const void* p, size_t i, bool isf32) {
    return isf32 ? ((const float*)p)[i] : b2f(((const u16*)p)[i]);
}
__device__ __forceinline__ float4 ld4(const void* p, size_t i, bool isf32) {
    if (isf32) return *(const float4*)((const float*)p + i);
    ushort4 v = *(const ushort4*)((const u16*)p + i);
    return make_float4(b2f(v.x), b2f(v.y), b2f(v.z), b2f(v.w));
}

// async global->LDS, 16B per lane (dest = wave-uniform base + lane*16)
__device__ __forceinline__ void gll16(const void* g, void* l) {
    __builtin_amdgcn_global_load_lds(
        (const __attribute__((address_space(1))) void*)g,
        (__attribute__((address_space(3))) void*)l, 16, 0, 0);
}

// ============================================================================
// Dtype detection: sample even-indexed u16s of W1 (512*1024 randn*0.02 elems).
// bf16 data -> exponent field in [100,130] for ~100% of samples.
// f32 data  -> even u16s are mantissa halves, exponent ~uniform -> ~12%.
// ============================================================================
__global__ __launch_bounds__(256) void k_detect(const void* w1, int* flag)
{
    __shared__ int red[256];
    const int tid = threadIdx.x;
    const u16* p = (const u16*)w1;
    int good = 0;
    for (int i = 0; i < 16; ++i) {
        u16 v = p[(size_t)(tid * 16 + i) * 2];   // even index
        int e = (v >> 7) & 0xFF;
        good += (e >= 100 && e <= 130) ? 1 : 0;
    }
    red[tid] = good;
    __syncthreads();
    for (int off = 128; off > 0; off >>= 1) {
        if (tid < off) red[tid] += red[tid + off];
        __syncthreads();
    }
    if (tid == 0) *flag = (red[0] < 2048) ? 1 : 0;   // <50% plausible => f32
}

// ============================================================================
// Gather + split: A1 = embed[seq] as bf16 hi/lo row-major [NM][512].
// ============================================================================
__global__ __launch_bounds__(256) void k_splitA(const int* __restrict__ seq,
                                                const void* __restrict__ embed,
                                                u16* __restrict__ hi,
                                                u16* __restrict__ lo,
                                                const int* __restrict__ dflag)
{
    const bool isf32 = (*dflag != 0);
    int gid = blockIdx.x * 256 + threadIdx.x;   // one 8-elem chunk per thread
    int m = gid >> 6;
    int kc = (gid & 63) * 8;
    size_t src = (size_t)seq[m] * ND + kc;
    float4 a = ld4(embed, src, isf32);
    float4 b = ld4(embed, src + 4, isf32);
    float v[8] = {a.x, a.y, a.z, a.w, b.x, b.y, b.z, b.w};
    u16 hv[8], lv[8];
#pragma unroll
    for (int i = 0; i < 8; ++i) {
        hv[i] = f2b(v[i]);
        lv[i] = f2b(v[i] - b2f(hv[i]));
    }
    size_t dst = (size_t)m * ND + kc;
    *(ushort4*)&hi[dst]     = make_ushort4(hv[0], hv[1], hv[2], hv[3]);
    *(ushort4*)&hi[dst + 4] = make_ushort4(hv[4], hv[5], hv[6], hv[7]);
    *(ushort4*)&lo[dst]     = make_ushort4(lv[0], lv[1], lv[2], lv[3]);
    *(ushort4*)&lo[dst + 4] = make_ushort4(lv[4], lv[5], lv[6], lv[7]);
}

// ============================================================================
// Transpose + split: src [R][C] (f32 or bf16) -> hiT/loT [C][R] bf16.
// ============================================================================
__global__ __launch_bounds__(256) void k_splitWT(const void* __restrict__ src,
                                                 u16* __restrict__ hiT,
                                                 u16* __restrict__ loT,
                                                 int R, int C,
                                                 const int* __restrict__ dflag)
{
    const bool isf32 = (*dflag != 0);
    __shared__ float tile[32][33];
    const int tx = threadIdx.x & 31, ty = threadIdx.x >> 5;   // 32 x 8
    const int c0 = blockIdx.x * 32, r0 = blockIdx.y * 32;
#pragma unroll
    for (int k = 0; k < 4; ++k)
        tile[ty + 8 * k][tx] = ld1(src, (size_t)(r0 + ty + 8 * k) * C + c0 + tx, isf32);
    __syncthreads();
#pragma unroll
    for (int k = 0; k < 4; ++k) {
        float v = tile[tx][ty + 8 * k];
        u16 h = f2b(v);
        u16 l = f2b(v - b2f(h));
        size_t o = (size_t)(c0 + ty + 8 * k) * R + r0 + tx;
        hiT[o] = h;
        loT[o] = l;
    }
}

// ============================================================================
// Split-bf16 MFMA GEMM, counted-vmcnt double-buffered pipeline (T3+T4 min):
//   iter t: issue loads(t+1) -> buf^1; s_waitcnt vmcnt(8)  [tile-t loads done,
//           tile-t+1 stays IN FLIGHT]; s_barrier; ds_read+MFMA(buf);
//           lgkmcnt(0); s_barrier.
// No vmcnt(0) drain in the main loop -- prefetch gets a full K-step to land.
// C[128x128] = A[m][K] @ B^T[n][K] via Ah*Bh + Al*Bh + Ah*Bl.
// 256 thr = 4 waves (2x2 quadrants of 64x64), mfma_f32_16x16x32_bf16.
// 1-D grid, bijective XCD swizzle, N-tile fast => A panels L2-resident.
// ============================================================================
template<int KSTEPS, int NTILES, bool SPLITOUT>
__global__ __launch_bounds__(256) void k_mfma(
    const u16* __restrict__ Ahi, const u16* __restrict__ Alo,
    const u16* __restrict__ Bhi, const u16* __restrict__ Blo,
    const void* __restrict__ bias,
    u16* __restrict__ Chi, u16* __restrict__ Clo,
    float* __restrict__ Cf, const int* __restrict__ seqg,
    const void* __restrict__ embed, int mG0,
    const int* __restrict__ dflag)
{
    constexpr int K = KSTEPS * 32;
    const bool isf32 = (*dflag != 0);
    __shared__ __align__(16) u16 lds[2][16384];  // dbuf x [Ahi|Alo|Bhi|Blo] (8KB each)
    const int tid = threadIdx.x;

    // bijective XCD swizzle (gridDim.x % 8 == 0): XCD k gets contiguous wg range
    const int lin = blockIdx.x;
    const int qx = gridDim.x >> 3;
    const int wg = (lin & 7) * qx + (lin >> 3);
    const int m0 = (wg / NTILES) * 128;   // chunk-local
    const int n0 = (wg % NTILES) * 128;

    const int wid = tid >> 6, lane = tid & 63;
    const int wm = wid >> 1, wn = wid & 1;

    // staging: chunk ch = c*256+tid maps to (mt=ch>>6, r=ch&15, g=(ch>>4)&3);
    // LDS chunk index = mt*64 + (r + 16g)  == fragment lane order.
    const int ch0 = tid, ch1 = tid + 256;
    const int ar0 = ((ch0 >> 6) << 4) + (ch0 & 15);
    const int ar1 = ((ch1 >> 6) << 4) + (ch1 & 15);
    const int ag0 = ((ch0 >> 4) & 3) * 8;
    const int ag1 = ((ch1 >> 4) & 3) * 8;
    const u16* pAh0 = Ahi + (size_t)(m0 + ar0) * K + ag0;
    const u16* pAh1 = Ahi + (size_t)(m0 + ar1) * K + ag1;
    const u16* pAl0 = Alo + (size_t)(m0 + ar0) * K + ag0;
    const u16* pAl1 = Alo + (size_t)(m0 + ar1) * K + ag1;
    const u16* pBh0 = Bhi + (size_t)(n0 + ar0) * K + ag0;
    const u16* pBh1 = Bhi + (size_t)(n0 + ar1) * K + ag1;
    const u16* pBl0 = Blo + (size_t)(n0 + ar0) * K + ag0;
    const u16* pBl1 = Blo + (size_t)(n0 + ar1) * K + ag1;

    f32x4 acc[4][4];
#pragma unroll
    for (int i = 0; i < 4; ++i)
#pragma unroll
        for (int j = 0; j < 4; ++j) {
            acc[i][j][0] = 0.f; acc[i][j][1] = 0.f;
            acc[i][j][2] = 0.f; acc[i][j][3] = 0.f;
        }

#define ISSUE8(o, buf) { u16* d_ = &lds[buf][tid * 8]; \
        gll16(pAh0 + (o), d_);          gll16(pAh1 + (o), d_ + 2048); \
        gll16(pAl0 + (o), d_ + 4096);   gll16(pAl1 + (o), d_ + 6144); \
        gll16(pBh0 + (o), d_ + 8192);   gll16(pBh1 + (o), d_ + 10240); \
        gll16(pBl0 + (o), d_ + 12288);  gll16(pBl1 + (o), d_ + 14336); }

    // prologue: stage K-step 0 into buf 0 (stays in flight until iter 0's wait)
    ISSUE8(0, 0);

    int cur = 0;
    for (int ks = 0; ks < KSTEPS; ++ks) {
        if (ks + 1 < KSTEPS) {
            ISSUE8((ks + 1) * 32, cur ^ 1);     // 8 newer vmem ops in flight
            __builtin_amdgcn_sched_barrier(0);
            asm volatile("s_waitcnt vmcnt(8)" ::: "memory");  // tile ks landed
        } else {
            asm volatile("s_waitcnt vmcnt(0)" ::: "memory");  // final tile
        }
        __builtin_amdgcn_s_barrier();            // all waves' tile-ks in LDS
        asm volatile("" ::: "memory");           // no LDS reads above barrier
        const u16* fA = &lds[cur][wm * 2048 + lane * 8];
        const u16* fB = &lds[cur][8192 + wn * 2048 + lane * 8];
        bf16x8 ah[4], al[4];
#pragma unroll
        for (int i = 0; i < 4; ++i) {
            ah[i] = *(const bf16x8*)(fA + i * 512);
            al[i] = *(const bf16x8*)(fA + 4096 + i * 512);
        }
#pragma unroll
        for (int j = 0; j < 4; ++j) {
            bf16x8 bh = *(const bf16x8*)(fB + j * 512);
            bf16x8 bl = *(const bf16x8*)(fB + 4096 + j * 512);
#pragma unroll
            for (int i = 0; i < 4; ++i)
                acc[i][j] = __builtin_amdgcn_mfma_f32_16x16x32_bf16(ah[i], bh, acc[i][j], 0, 0, 0);
#pragma unroll
            for (int i = 0; i < 4; ++i)
                acc[i][j] = __builtin_amdgcn_mfma_f32_16x16x32_bf16(al[i], bh, acc[i][j], 0, 0, 0);
#pragma unroll
            for (int i = 0; i < 4; ++i)
                acc[i][j] = __builtin_amdgcn_mfma_f32_16x16x32_bf16(ah[i], bl, acc[i][j], 0, 0, 0);
        }
        __builtin_amdgcn_sched_barrier(0);
        asm volatile("s_waitcnt lgkmcnt(0)" ::: "memory");  // this wave's ds_reads done
        __builtin_amdgcn_s_barrier();            // buf cur free for loads(ks+2)
        cur ^= 1;
    }
#undef ISSUE8

    // ---- epilogue. C/D layout: col = lane&15, row = (lane>>4)*4 + reg ----
    const int lr = (lane >> 4) * 4;
    const int lc = lane & 15;
    if (SPLITOUT) {
#pragma unroll
        for (int j = 0; j < 4; ++j) {
            int col = n0 + wn * 64 + j * 16 + lc;
            float bv = ld1(bias, col, isf32);
#pragma unroll
            for (int i = 0; i < 4; ++i) {
                int row = m0 + wm * 64 + i * 16 + lr;
#pragma unroll
                for (int r = 0; r < 4; ++r) {
                    float v = fmaxf(acc[i][j][r] + bv, 0.f);
                    u16 hu = f2b(v);
                    Chi[(size_t)(row + r) * 1024 + col] = hu;
                    Clo[(size_t)(row + r) * 1024 + col] = f2b(v - b2f(hu));
                }
            }
        }
    } else {
        int* sSeq = (int*)&lds[0][0];   // reuse LDS (loop ended with barrier)
        if (tid < 128) sSeq[tid] = seqg[mG0 + m0 + tid];
        __syncthreads();
#pragma unroll
        for (int j = 0; j < 4; ++j) {
            int col = n0 + wn * 64 + j * 16 + lc;
            float bv = ld1(bias, col, isf32);
#pragma unroll
            for (int i = 0; i < 4; ++i) {
                int br = wm * 64 + i * 16 + lr;
#pragma unroll
                for (int r = 0; r < 4; ++r) {
                    float v = acc[i][j][r] + bv
                            + ld1(embed, (size_t)sSeq[br + r] * ND + col, isf32);
                    Cf[(size_t)(mG0 + m0 + br + r) * ND + col] = v;
                }
            }
        }
    }
}

// ============================================================================
// Fused LayerNorm + gate partial dots, one wave per row, barrier-free.
// h[m] <- LN(h[m]); g1[m] = LN·gW[0:512]; g2[m] = LN·gW[512:1024]
// ============================================================================
__global__ __launch_bounds__(256) void k_lng(float* __restrict__ h,
                                             const void* __restrict__ lg,
                                             const void* __restrict__ lb,
                                             const void* __restrict__ gW,
                                             float* __restrict__ g1,
                                             float* __restrict__ g2,
                                             const int* __restrict__ dflag)
{
    const bool isf32 = (*dflag != 0);
    const int lane = threadIdx.x & 63;
    const int m = blockIdx.x * 4 + (threadIdx.x >> 6);
    float* row = h + (size_t)m * ND;
    const int d = lane * 8;
    float4 x0 = *(float4*)(row + d);
    float4 x1 = *(float4*)(row + d + 4);
    float s = x0.x + x0.y + x0.z + x0.w + x1.x + x1.y + x1.z + x1.w;
#pragma unroll
    for (int off = 32; off > 0; off >>= 1) s += __shfl_xor(s, off, 64);
    float mean = s * (1.f / 512.f);
    float d0 = x0.x - mean, d1 = x0.y - mean, d2 = x0.z - mean, d3 = x0.w - mean;
    float d4 = x1.x - mean, d5 = x1.y - mean, d6 = x1.z - mean, d7 = x1.w - mean;
    float vs = d0 * d0 + d1 * d1 + d2 * d2 + d3 * d3
             + d4 * d4 + d5 * d5 + d6 * d6 + d7 * d7;
#pragma unroll
    for (int off = 32; off > 0; off >>= 1) vs += __shfl_xor(vs, off, 64);
    float rstd = rsqrtf(vs * (1.f / 512.f) + 1e-5f);
    float4 ga = ld4(lg, d, isf32), gb = ld4(lg, d + 4, isf32);
    float4 ba = ld4(lb, d, isf32), bb = ld4(lb, d + 4, isf32);
    float o0 = d0 * rstd * ga.x + ba.x;
    float o1 = d1 * rstd * ga.y + ba.y;
    float o2 = d2 * rstd * ga.z + ba.z;
    float o3 = d3 * rstd * ga.w + ba.w;
    float o4 = d4 * rstd * gb.x + bb.x;
    float o5 = d5 * rstd * gb.y + bb.y;
    float o6 = d6 * rstd * gb.z + bb.z;
    float o7 = d7 * rstd * gb.w + bb.w;
    *(float4*)(row + d)     = make_float4(o0, o1, o2, o3);
    *(float4*)(row + d + 4) = make_float4(o4, o5, o6, o7);
    float4 wa = ld4(gW, d, isf32), wb = ld4(gW, d + 4, isf32);
    float4 va = ld4(gW, 512 + d, isf32), vb = ld4(gW, 512 + d + 4, isf32);
    float s1 = o0 * wa.x + o1 * wa.y + o2 * wa.z + o3 * wa.w
             + o4 * wb.x + o5 * wb.y + o6 * wb.z + o7 * wb.w;
    float s2 = o0 * va.x + o1 * va.y + o2 * va.z + o3 * va.w
             + o4 * vb.x + o5 * vb.y + o6 * vb.z + o7 * vb.w;
#pragma unroll
    for (int off = 32; off > 0; off >>= 1) {
        s1 += __shfl_down(s1, off, 64);
        s2 += __shfl_down(s2, off, 64);
    }
    if (lane == 0) { g1[m] = s1; g2[m] = s2; }
}

// ============================================================================
// Fused tail (one block per batch): gate logits -> exact top-256 radix-select
// -> q = h[b,T-1]@qW+qb -> scores/softmax -> ctx.  All intermediates in LDS.
// Downstream softmax+weighted-sum is permutation-invariant => only the top-k
// SET matters; ties at threshold resolved by lowest index (rare slow path).
// ============================================================================
__global__ __launch_bounds__(256) void k_tail(const float* __restrict__ h,
                                              const float* __restrict__ g1,
                                              const float* __restrict__ g2,
                                              const void* __restrict__ qW,
                                              const void* __restrict__ qb,
                                              float* __restrict__ ctx,
                                              const int* __restrict__ dflag)
{
    const bool isf32 = (*dflag != 0);
    const int b = blockIdx.x, tid = threadIdx.x;
    const int lane = tid & 63, wv = tid >> 6;
    __shared__ unsigned keys[NT];      // 16 KB
    __shared__ float g2s[NT];          // 16 KB (reused as hlast later)
    __shared__ float qv[ND];
    __shared__ float sc[NSLOTS];
    __shared__ int   sidx[NSLOTS];
    __shared__ int   red[4];
    __shared__ float fred[4];
    __shared__ int   s_cnt;

    // ---- gate logits -> sortable keys ----
    const float* g2r = g2 + (size_t)b * NT;
    const float* g1r = g1 + (size_t)b * NT;
    for (int i = tid; i < NT; i += 256) g2s[i] = g2r[i];
    __syncthreads();
    for (int i = tid; i < NT; i += 256) {
        int cnt = min(NK, NT - 1 - i);
        float s = 0.f;
        for (int j = 1; j <= cnt; ++j) s += g2s[i + j];
        float gate = g1r[i] + ((cnt > 0) ? s / (float)cnt : 0.f);
        unsigned u = __float_as_uint(gate);
        u = (u & 0x80000000u) ? ~u : (u | 0x80000000u);
        keys[i] = u;
    }
    __syncthreads();

    // ---- radix select threshold ----
    unsigned sel = 0;
    for (int bit = 31; bit >= 0; --bit) {
        unsigned cand = sel | (1u << bit);
        int c = 0;
        for (int i = tid; i < NT; i += 256) c += (keys[i] >= cand) ? 1 : 0;
#pragma unroll
        for (int off = 32; off > 0; off >>= 1) c += __shfl_down(c, off, 64);
        if (lane == 0) red[wv] = c;
        __syncthreads();
        int total = red[0] + red[1] + red[2] + red[3];
        __syncthreads();
        if (total >= NSLOTS) sel = cand;
    }
    if (tid == 0) s_cnt = 0;
    __syncthreads();
    for (int i = tid; i < NT; i += 256)
        if (keys[i] > sel) sidx[atomicAdd(&s_cnt, 1)] = i;
    __syncthreads();
    const int base = s_cnt;
    int tc = 0;
    for (int i = tid; i < NT; i += 256) tc += (keys[i] == sel) ? 1 : 0;
#pragma unroll
    for (int off = 32; off > 0; off >>= 1) tc += __shfl_down(tc, off, 64);
    if (lane == 0) red[wv] = tc;
    __syncthreads();
    int tcnt = red[0] + red[1] + red[2] + red[3];
    if (tcnt == NSLOTS - base) {
        for (int i = tid; i < NT; i += 256)
            if (keys[i] == sel) sidx[atomicAdd(&s_cnt, 1)] = i;
    } else if (tid == 0) {   // rare: more ties than slots -> lowest indices
        int p = base;
        for (int i = 0; i < NT && p < NSLOTS; ++i)
            if (keys[i] == sel) sidx[p++] = i;
    }
    __syncthreads();

    // ---- q = h[b,T-1] @ qW + qb ----
    const float* hb = h + (size_t)b * NT * ND;
    const float* hlast = hb + (size_t)(NT - 1) * ND;
    float* hl = g2s;   // reuse (g2s no longer needed)
    hl[tid] = hlast[tid];
    hl[256 + tid] = hlast[256 + tid];
    __syncthreads();
    for (int j = tid; j < ND; j += 256) {
        float acc = ld1(qb, j, isf32);
        for (int d = 0; d < ND; ++d) acc += hl[d] * ld1(qW, (size_t)d * ND + j, isf32);
        qv[j] = acc;
    }
    __syncthreads();

    // ---- scores + softmax (256 slots <-> 256 threads) ----
    float s = 0.f;
    {
        const float* row = hb + (size_t)sidx[tid] * ND;
        for (int d = 0; d < ND; d += 4) {
            float4 hv = *(const float4*)(row + d);
            float4 qq = *(const float4*)(qv + d);
            s += hv.x * qq.x + hv.y * qq.y + hv.z * qq.z + hv.w * qq.w;
        }
    }
    float mx = s;
#pragma unroll
    for (int off = 32; off > 0; off >>= 1) mx = fmaxf(mx, __shfl_xor(mx, off, 64));
    if (lane == 0) fred[wv] = mx;
    __syncthreads();
    mx = fmaxf(fmaxf(fred[0], fred[1]), fmaxf(fred[2], fred[3]));
    __syncthreads();
    float e = expf(s - mx);
    sc[tid] = e;
    float se = e;
#pragma unroll
    for (int off = 32; off > 0; off >>= 1) se += __shfl_xor(se, off, 64);
    if (lane == 0) fred[wv] = se;
    __syncthreads();
    float inv = 1.f / (fred[0] + fred[1] + fred[2] + fred[3]);

    // ---- ctx = sum_m sc[m] * h[sidx[m]] ----
    for (int d = tid; d < ND; d += 256) {
        float acc = 0.f;
        for (int m = 0; m < NSLOTS; ++m) acc += sc[m] * hb[(size_t)sidx[m] * ND + d];
        ctx[b * ND + d] = acc * inv;
    }
}

// ============================================================================
// out[b][v] = ctx[b] · out_W[:,v] + out_b[v]   (1 column per thread, 197 wgs)
// ============================================================================
__global__ __launch_bounds__(256) void k_out(const float* __restrict__ ctx,
                                             const void* __restrict__ outW,
                                             const void* __restrict__ outb,
                                             void* __restrict__ out,
                                             const int* __restrict__ dflag)
{
    const bool isf32 = (*dflag != 0);
    __shared__ float cs[NB * ND];
    const int tid = threadIdx.x;
    for (int i = tid; i < NB * ND; i += 256) cs[i] = ctx[i];
    __syncthreads();
    int v = blockIdx.x * 256 + tid;
    if (v >= NV) return;
    float acc[NB];
#pragma unroll
    for (int bb = 0; bb < NB; ++bb) acc[bb] = 0.f;
    for (int d = 0; d < ND; ++d) {
        float w = ld1(outW, (size_t)d * NV + v, isf32);
#pragma unroll
        for (int bb = 0; bb < NB; ++bb) acc[bb] += cs[bb * ND + d] * w;
    }
    float ob = ld1(outb, v, isf32);
#pragma unroll
    for (int bb = 0; bb < NB; ++bb) {
        float r = acc[bb] + ob;
        size_t o = (size_t)bb * NV + v;
        if (isf32) ((float*)out)[o] = r;
        else       ((u16*)out)[o]   = f2b(r);
    }
}

// ============================================================================
extern "C" void kernel_launch(void* const* d_in, const int* in_sizes, int n_in,
                              void* d_out, int out_size, void* d_ws, size_t ws_size,
                              hipStream_t stream)
{
    const int*  seq   = (const int*)d_in[0];
    const void* embed = d_in[1];
    const void* W1    = d_in[2];
    const void* b1    = d_in[3];
    const void* W2    = d_in[4];
    const void* b2v   = d_in[5];
    const void* lng   = d_in[6];
    const void* lnb   = d_in[7];
    const void* gateW = d_in[8];
    // d_in[9] = gate_b (constant shift, irrelevant for top-k ordering)
    const void* qW    = d_in[10];
    const void* qb    = d_in[11];
    const void* outW  = d_in[12];
    const void* outb  = d_in[13];

    // ---- ws layout: flag + small buffers, h (f32), split operand arrays, t1 ----
    float* ws   = (float*)d_ws;
    int*   flag = (int*)ws;                    // ws[0..3] (16B pad)
    float* g1   = ws + 4;                      // NM
    float* g2   = g1 + NM;                     // NM
    float* ctx  = g2 + NM;                     // NB*ND
    float* h    = ctx + NB * ND;               // NM*ND f32 (64 MiB)
    u16* A1hi   = (u16*)(h + (size_t)NM * ND); // NM*512 bf16 (32 MiB)
    u16* A1lo   = A1hi + (size_t)NM * ND;      // 32 MiB
    u16* W1thi  = A1lo + (size_t)NM * ND;      // [1024][512] (1 MiB)
    u16* W1tlo  = W1thi + (size_t)1024 * 512;
    u16* W2thi  = W1tlo + (size_t)1024 * 512;  // [512][1024]
    u16* W2tlo  = W2thi + (size_t)1024 * 512;
    u16* t1hi   = W2tlo + (size_t)1024 * 512;  // [MC][1024] bf16 hi

    // ws-adaptive M-chunk for the FFN intermediate (t1 split pair = MC*4096 B).
    // Branch depends only on ws_size: graph-safe.
    const size_t usedB = (size_t)((char*)t1hi - (char*)d_ws);
    int MC;
    if      (ws_size >= usedB + (size_t)32768 * 4096) MC = 32768;
    else if (ws_size >= usedB + (size_t)16384 * 4096) MC = 16384;
    else if (ws_size >= usedB + (size_t)8192  * 4096) MC = 8192;
    else                                              MC = 4096;
    u16* t1lo = t1hi + (size_t)MC * 1024;

    k_detect<<<1, 256, 0, stream>>>(W1, flag);
    k_splitA<<<NM / 4, 256, 0, stream>>>(seq, embed, A1hi, A1lo, flag);
    k_splitWT<<<dim3(32, 16), 256, 0, stream>>>(W1, W1thi, W1tlo, 512, 1024, flag);
    k_splitWT<<<dim3(16, 32), 256, 0, stream>>>(W2, W2thi, W2tlo, 1024, 512, flag);

    for (int m0g = 0; m0g < NM; m0g += MC) {
        // GEMM1: t1 = relu(A1 @ W1 + b1), split-bf16 output  (grid = MC/128 * 8)
        k_mfma<16, 8, true><<<(MC / 128) * 8, 256, 0, stream>>>(
            A1hi + (size_t)m0g * ND, A1lo + (size_t)m0g * ND,
            W1thi, W1tlo, b1,
            t1hi, t1lo,
            nullptr, nullptr, nullptr, 0, flag);
        // GEMM2: h = t1 @ W2 + b2 + embed[seq] (exact f32 residual)
        k_mfma<32, 4, false><<<(MC / 128) * 4, 256, 0, stream>>>(
            t1hi, t1lo,
            W2thi, W2tlo, b2v,
            nullptr, nullptr,
            h, seq, embed, m0g, flag);
    }

    k_lng<<<NM / 4, 256, 0, stream>>>(h, lng, lnb, gateW, g1, g2, flag);
    k_tail<<<NB, 256, 0, stream>>>(h, g1, g2, qW, qb, ctx, flag);
    k_out<<<(NV + 255) / 256, 256, 0, stream>>>(ctx, outW, outb, d_out, flag);
}

// Round 4
// 844.998 us; speedup vs baseline: 2.0329x; 1.1011x over previous
//
#include <hip/hip_runtime.h>

typedef unsigned short u16;
typedef __attribute__((ext_vector_type(8))) short bf16x8;   // 8 bf16 = 4 VGPRs
typedef __attribute__((ext_vector_type(4))) float f32x4;

// ---- problem constants ----
constexpr int NV = 50257;   // vocab
constexpr int ND = 512;     // hidden
constexpr int NT = 4096;    // seq len
constexpr int NB = 8;       // batch
constexpr int NM = NB * NT; // 32768 tokens
constexpr int NSLOTS = 256;
constexpr int NK = 8;       // lookahead window

__device__ __forceinline__ float b2f(u16 u) { return __uint_as_float(((unsigned)u) << 16); }
__device__ __forceinline__ u16 f2b(float f) {
    unsigned u = __float_as_uint(f);
    u += 0x7FFFu + ((u >> 16) & 1u);   // round-to-nearest-even
    return (u16)(u >> 16);
}

// Dual-dtype element loads. isf32 is wave-uniform (device-detected flag).
__device__ __forceinline__ float ld1(const void* p, size_t i, bool isf32) {
    return isf32 ? ((const float*)p)[i] : b2f(((const u16*)p)[i]);
}
__device__ __forceinline__ float4 ld4(const void* p, size_t i, bool isf32) {
    if (isf32) return *(const float4*)((const float*)p + i);
    ushort4 v = *(const ushort4*)((const u16*)p + i);
    return make_float4(b2f(v.x), b2f(v.y), b2f(v.z), b2f(v.w));
}

// async global->LDS, 16B per lane (dest = wave-uniform base + lane*16)
__device__ __forceinline__ void gll16(const void* g, void* l) {
    __builtin_amdgcn_global_load_lds(
        (const __attribute__((address_space(1))) void*)g,
        (__attribute__((address_space(3))) void*)l, 16, 0, 0);
}

// ============================================================================
// Dtype detection (device flag used by shared kernels): sample even u16s of W1.
// ============================================================================
__global__ __launch_bounds__(256) void k_detect(const void* w1, int* flag)
{
    __shared__ int red[256];
    const int tid = threadIdx.x;
    const u16* p = (const u16*)w1;
    int good = 0;
    for (int i = 0; i < 16; ++i) {
        u16 v = p[(size_t)(tid * 16 + i) * 2];   // even index
        int e = (v >> 7) & 0xFF;
        good += (e >= 100 && e <= 130) ? 1 : 0;
    }
    red[tid] = good;
    __syncthreads();
    for (int off = 128; off > 0; off >>= 1) {
        if (tid < off) red[tid] += red[tid + off];
        __syncthreads();
    }
    if (tid == 0) *flag = (red[0] < 2048) ? 1 : 0;   // <50% plausible => f32
}

// ============================================================================
// Gather + split: A1 = embed[seq] as bf16 hi/lo row-major (GENERIC path only).
// ============================================================================
__global__ __launch_bounds__(256) void k_splitA(const int* __restrict__ seq,
                                                const void* __restrict__ embed,
                                                u16* __restrict__ hi,
                                                u16* __restrict__ lo,
                                                const int* __restrict__ dflag)
{
    const bool isf32 = (*dflag != 0);
    int gid = blockIdx.x * 256 + threadIdx.x;   // one 8-elem chunk per thread
    int m = gid >> 6;
    int kc = (gid & 63) * 8;
    size_t src = (size_t)seq[m] * ND + kc;
    float4 a = ld4(embed, src, isf32);
    float4 b = ld4(embed, src + 4, isf32);
    float v[8] = {a.x, a.y, a.z, a.w, b.x, b.y, b.z, b.w};
    u16 hv[8], lv[8];
#pragma unroll
    for (int i = 0; i < 8; ++i) {
        hv[i] = f2b(v[i]);
        lv[i] = f2b(v[i] - b2f(hv[i]));
    }
    size_t dst = (size_t)m * ND + kc;
    *(ushort4*)&hi[dst]     = make_ushort4(hv[0], hv[1], hv[2], hv[3]);
    *(ushort4*)&hi[dst + 4] = make_ushort4(hv[4], hv[5], hv[6], hv[7]);
    *(ushort4*)&lo[dst]     = make_ushort4(lv[0], lv[1], lv[2], lv[3]);
    *(ushort4*)&lo[dst + 4] = make_ushort4(lv[4], lv[5], lv[6], lv[7]);
}

// ============================================================================
// Transpose + split: src [R][C] (f32 or bf16) -> hiT/loT [C][R] bf16.
// (bf16 input: hiT = exact transpose, loT = 0.)
// ============================================================================
__global__ __launch_bounds__(256) void k_splitWT(const void* __restrict__ src,
                                                 u16* __restrict__ hiT,
                                                 u16* __restrict__ loT,
                                                 int R, int C,
                                                 const int* __restrict__ dflag)
{
    const bool isf32 = (*dflag != 0);
    __shared__ float tile[32][33];
    const int tx = threadIdx.x & 31, ty = threadIdx.x >> 5;   // 32 x 8
    const int c0 = blockIdx.x * 32, r0 = blockIdx.y * 32;
#pragma unroll
    for (int k = 0; k < 4; ++k)
        tile[ty + 8 * k][tx] = ld1(src, (size_t)(r0 + ty + 8 * k) * C + c0 + tx, isf32);
    __syncthreads();
#pragma unroll
    for (int k = 0; k < 4; ++k) {
        float v = tile[tx][ty + 8 * k];
        u16 h = f2b(v);
        u16 l = f2b(v - b2f(h));
        size_t o = (size_t)(c0 + ty + 8 * k) * R + r0 + tx;
        hiT[o] = h;
        loT[o] = l;
    }
}

// ============================================================================
// bf16 FAST-PATH MFMA GEMM (host-verified bf16 inputs), m97 structure:
// single 16/24 KB LDS buffer, { stage -> sync -> ds_read+MFMA -> sync } per
// K-step; occupancy (5-6 blocks/CU) provides the latency hiding (m97/m114).
// NPROD=1: C = A@Bt^T (A exact bf16).  NPROD=2: C = (Ah+Al)@Bt^T.
// GATHER: A rows come straight from embed via per-lane seq-gathered
// global_load_lds source addresses (kills the k_splitA pass).
// SPLITOUT: relu(acc+bias) -> hi/lo bf16 pair (t1).  else: acc+bias+embed
// residual -> f32 h.  Bit-identical to the generic 3-product path for bf16
// inputs (dropped products are exactly zero; accumulation order preserved).
// ============================================================================
template<int KSTEPS, int NTILES, bool GATHER, bool SPLITOUT, int NPROD>
__global__ __launch_bounds__(256) void k_bmfma(
    const u16* __restrict__ Ah, const u16* __restrict__ Al,
    const int* __restrict__ seqg,
    const u16* __restrict__ Bt, const u16* __restrict__ bias,
    u16* __restrict__ Chi, u16* __restrict__ Clo,
    float* __restrict__ Cf, const u16* __restrict__ embed,
    int mG0)
{
    constexpr int K = KSTEPS * 32;
    constexpr int BOFF = (NPROD == 2) ? 8192 : 4096;   // B region base (u16 idx)
    __shared__ __align__(16) u16 lds[(NPROD == 2) ? 12288 : 8192];
    __shared__ int sSeq[128];
    const int tid = threadIdx.x;

    // bijective XCD swizzle (gridDim.x % 8 == 0)
    const int lin = blockIdx.x;
    const int qx = gridDim.x >> 3;
    const int wg = (lin & 7) * qx + (lin >> 3);
    const int m0 = (wg / NTILES) * 128;   // chunk-local
    const int n0 = (wg % NTILES) * 128;

    const int wid = tid >> 6, lane = tid & 63;
    const int wm = wid >> 1, wn = wid & 1;

    if (tid < 128) sSeq[tid] = seqg[mG0 + m0 + tid];
    __syncthreads();

    // fragment-order staging map: chunk ch -> (mt=ch>>6, r=ch&15, g=(ch>>4)&3)
    const int ch0 = tid, ch1 = tid + 256;
    const int ar0 = ((ch0 >> 6) << 4) + (ch0 & 15);   // rows 0..63
    const int ar1 = ((ch1 >> 6) << 4) + (ch1 & 15);   // rows 64..127
    const int ag0 = ((ch0 >> 4) & 3) * 8;
    const int ag1 = ((ch1 >> 4) & 3) * 8;
    size_t aB0, aB1;
    if (GATHER) {
        aB0 = (size_t)sSeq[ar0] * K + ag0;
        aB1 = (size_t)sSeq[ar1] * K + ag1;
    } else {
        aB0 = (size_t)(m0 + ar0) * K + ag0;
        aB1 = (size_t)(m0 + ar1) * K + ag1;
    }
    const size_t bB0 = (size_t)(n0 + ar0) * K + ag0;
    const size_t bB1 = (size_t)(n0 + ar1) * K + ag1;

    f32x4 acc[4][4];
#pragma unroll
    for (int i = 0; i < 4; ++i)
#pragma unroll
        for (int j = 0; j < 4; ++j) {
            acc[i][j][0] = 0.f; acc[i][j][1] = 0.f;
            acc[i][j][2] = 0.f; acc[i][j][3] = 0.f;
        }

    u16* d0 = lds + tid * 8;
    const u16* fA = lds + wm * 2048 + lane * 8;
    const u16* fB = lds + BOFF + wn * 2048 + lane * 8;

    for (int ks = 0; ks < KSTEPS; ++ks) {
        const int o = ks * 32;
        gll16(Ah + aB0 + o, d0);
        gll16(Ah + aB1 + o, d0 + 2048);
        if (NPROD == 2) {
            gll16(Al + aB0 + o, d0 + 4096);
            gll16(Al + aB1 + o, d0 + 6144);
        }
        gll16(Bt + bB0 + o, d0 + BOFF);
        gll16(Bt + bB1 + o, d0 + BOFF + 2048);
        __syncthreads();   // vmcnt(0)+barrier: staged tile visible
        bf16x8 ah[4];
#pragma unroll
        for (int i = 0; i < 4; ++i) ah[i] = *(const bf16x8*)(fA + i * 512);
        bf16x8 al[4];
        if (NPROD == 2) {
#pragma unroll
            for (int i = 0; i < 4; ++i) al[i] = *(const bf16x8*)(fA + 4096 + i * 512);
        }
#pragma unroll
        for (int j = 0; j < 4; ++j) {
            bf16x8 bh = *(const bf16x8*)(fB + j * 512);
#pragma unroll
            for (int i = 0; i < 4; ++i)
                acc[i][j] = __builtin_amdgcn_mfma_f32_16x16x32_bf16(ah[i], bh, acc[i][j], 0, 0, 0);
            if (NPROD == 2) {
#pragma unroll
                for (int i = 0; i < 4; ++i)
                    acc[i][j] = __builtin_amdgcn_mfma_f32_16x16x32_bf16(al[i], bh, acc[i][j], 0, 0, 0);
            }
        }
        __syncthreads();   // LDS free for next stage
    }

    // ---- epilogue. C/D layout: col = lane&15, row = (lane>>4)*4 + reg ----
    const int lr = (lane >> 4) * 4;
    const int lc = lane & 15;
    if (SPLITOUT) {
#pragma unroll
        for (int j = 0; j < 4; ++j) {
            int col = n0 + wn * 64 + j * 16 + lc;
            float bv = b2f(bias[col]);
#pragma unroll
            for (int i = 0; i < 4; ++i) {
                int row = m0 + wm * 64 + i * 16 + lr;   // chunk-local t1 row
#pragma unroll
                for (int r = 0; r < 4; ++r) {
                    float v = fmaxf(acc[i][j][r] + bv, 0.f);
                    u16 hu = f2b(v);
                    Chi[(size_t)(row + r) * 1024 + col] = hu;
                    Clo[(size_t)(row + r) * 1024 + col] = f2b(v - b2f(hu));
                }
            }
        }
    } else {
#pragma unroll
        for (int j = 0; j < 4; ++j) {
            int col = n0 + wn * 64 + j * 16 + lc;
            float bv = b2f(bias[col]);
#pragma unroll
            for (int i = 0; i < 4; ++i) {
                int br = wm * 64 + i * 16 + lr;
#pragma unroll
                for (int r = 0; r < 4; ++r) {
                    float v = acc[i][j][r] + bv
                            + b2f(embed[(size_t)sSeq[br + r] * ND + col]);
                    Cf[(size_t)(mG0 + m0 + br + r) * ND + col] = v;
                }
            }
        }
    }
}

// ============================================================================
// GENERIC 3-product MFMA GEMM (f32 / unknown dtype fallback) — round-3 proven.
// ============================================================================
template<int KSTEPS, int NTILES, bool SPLITOUT>
__global__ __launch_bounds__(256) void k_mfma(
    const u16* __restrict__ Ahi, const u16* __restrict__ Alo,
    const u16* __restrict__ Bhi, const u16* __restrict__ Blo,
    const void* __restrict__ bias,
    u16* __restrict__ Chi, u16* __restrict__ Clo,
    float* __restrict__ Cf, const int* __restrict__ seqg,
    const void* __restrict__ embed, int mG0,
    const int* __restrict__ dflag)
{
    constexpr int K = KSTEPS * 32;
    const bool isf32 = (*dflag != 0);
    __shared__ __align__(16) u16 lds[2][16384];  // dbuf x [Ahi|Alo|Bhi|Blo]
    const int tid = threadIdx.x;
    const int lin = blockIdx.x;
    const int qx = gridDim.x >> 3;
    const int wg = (lin & 7) * qx + (lin >> 3);
    const int m0 = (wg / NTILES) * 128;
    const int n0 = (wg % NTILES) * 128;
    const int wid = tid >> 6, lane = tid & 63;
    const int wm = wid >> 1, wn = wid & 1;

    const int ch0 = tid, ch1 = tid + 256;
    const int ar0 = ((ch0 >> 6) << 4) + (ch0 & 15);
    const int ar1 = ((ch1 >> 6) << 4) + (ch1 & 15);
    const int ag0 = ((ch0 >> 4) & 3) * 8;
    const int ag1 = ((ch1 >> 4) & 3) * 8;
    const u16* pAh0 = Ahi + (size_t)(m0 + ar0) * K + ag0;
    const u16* pAh1 = Ahi + (size_t)(m0 + ar1) * K + ag1;
    const u16* pAl0 = Alo + (size_t)(m0 + ar0) * K + ag0;
    const u16* pAl1 = Alo + (size_t)(m0 + ar1) * K + ag1;
    const u16* pBh0 = Bhi + (size_t)(n0 + ar0) * K + ag0;
    const u16* pBh1 = Bhi + (size_t)(n0 + ar1) * K + ag1;
    const u16* pBl0 = Blo + (size_t)(n0 + ar0) * K + ag0;
    const u16* pBl1 = Blo + (size_t)(n0 + ar1) * K + ag1;

    f32x4 acc[4][4];
#pragma unroll
    for (int i = 0; i < 4; ++i)
#pragma unroll
        for (int j = 0; j < 4; ++j) {
            acc[i][j][0] = 0.f; acc[i][j][1] = 0.f;
            acc[i][j][2] = 0.f; acc[i][j][3] = 0.f;
        }

#define ISSUE8(o, buf) { u16* d_ = &lds[buf][tid * 8]; \
        gll16(pAh0 + (o), d_);          gll16(pAh1 + (o), d_ + 2048); \
        gll16(pAl0 + (o), d_ + 4096);   gll16(pAl1 + (o), d_ + 6144); \
        gll16(pBh0 + (o), d_ + 8192);   gll16(pBh1 + (o), d_ + 10240); \
        gll16(pBl0 + (o), d_ + 12288);  gll16(pBl1 + (o), d_ + 14336); }

    ISSUE8(0, 0);
    int cur = 0;
    for (int ks = 0; ks < KSTEPS; ++ks) {
        if (ks + 1 < KSTEPS) {
            ISSUE8((ks + 1) * 32, cur ^ 1);
            __builtin_amdgcn_sched_barrier(0);
            asm volatile("s_waitcnt vmcnt(8)" ::: "memory");
        } else {
            asm volatile("s_waitcnt vmcnt(0)" ::: "memory");
        }
        __builtin_amdgcn_s_barrier();
        asm volatile("" ::: "memory");
        const u16* fA = &lds[cur][wm * 2048 + lane * 8];
        const u16* fB = &lds[cur][8192 + wn * 2048 + lane * 8];
        bf16x8 ah[4], al[4];
#pragma unroll
        for (int i = 0; i < 4; ++i) {
            ah[i] = *(const bf16x8*)(fA + i * 512);
            al[i] = *(const bf16x8*)(fA + 4096 + i * 512);
        }
#pragma unroll
        for (int j = 0; j < 4; ++j) {
            bf16x8 bh = *(const bf16x8*)(fB + j * 512);
            bf16x8 bl = *(const bf16x8*)(fB + 4096 + j * 512);
#pragma unroll
            for (int i = 0; i < 4; ++i)
                acc[i][j] = __builtin_amdgcn_mfma_f32_16x16x32_bf16(ah[i], bh, acc[i][j], 0, 0, 0);
#pragma unroll
            for (int i = 0; i < 4; ++i)
                acc[i][j] = __builtin_amdgcn_mfma_f32_16x16x32_bf16(al[i], bh, acc[i][j], 0, 0, 0);
#pragma unroll
            for (int i = 0; i < 4; ++i)
                acc[i][j] = __builtin_amdgcn_mfma_f32_16x16x32_bf16(ah[i], bl, acc[i][j], 0, 0, 0);
        }
        __builtin_amdgcn_sched_barrier(0);
        asm volatile("s_waitcnt lgkmcnt(0)" ::: "memory");
        __builtin_amdgcn_s_barrier();
        cur ^= 1;
    }
#undef ISSUE8

    const int lr = (lane >> 4) * 4;
    const int lc = lane & 15;
    if (SPLITOUT) {
#pragma unroll
        for (int j = 0; j < 4; ++j) {
            int col = n0 + wn * 64 + j * 16 + lc;
            float bv = ld1(bias, col, isf32);
#pragma unroll
            for (int i = 0; i < 4; ++i) {
                int row = m0 + wm * 64 + i * 16 + lr;
#pragma unroll
                for (int r = 0; r < 4; ++r) {
                    float v = fmaxf(acc[i][j][r] + bv, 0.f);
                    u16 hu = f2b(v);
                    Chi[(size_t)(row + r) * 1024 + col] = hu;
                    Clo[(size_t)(row + r) * 1024 + col] = f2b(v - b2f(hu));
                }
            }
        }
    } else {
        int* sSeq = (int*)&lds[0][0];
        if (tid < 128) sSeq[tid] = seqg[mG0 + m0 + tid];
        __syncthreads();
#pragma unroll
        for (int j = 0; j < 4; ++j) {
            int col = n0 + wn * 64 + j * 16 + lc;
            float bv = ld1(bias, col, isf32);
#pragma unroll
            for (int i = 0; i < 4; ++i) {
                int br = wm * 64 + i * 16 + lr;
#pragma unroll
                for (int r = 0; r < 4; ++r) {
                    float v = acc[i][j][r] + bv
                            + ld1(embed, (size_t)sSeq[br + r] * ND + col, isf32);
                    Cf[(size_t)(mG0 + m0 + br + r) * ND + col] = v;
                }
            }
        }
    }
}

// ============================================================================
// Fused LayerNorm + gate partial dots, one wave per row, barrier-free.
// ============================================================================
__global__ __launch_bounds__(256) void k_lng(float* __restrict__ h,
                                             const void* __restrict__ lg,
                                             const void* __restrict__ lb,
                                             const void* __restrict__ gW,
                                             float* __restrict__ g1,
                                             float* __restrict__ g2,
                                             const int* __restrict__ dflag)
{
    const bool isf32 = (*dflag != 0);
    const int lane = threadIdx.x & 63;
    const int m = blockIdx.x * 4 + (threadIdx.x >> 6);
    float* row = h + (size_t)m * ND;
    const int d = lane * 8;
    float4 x0 = *(float4*)(row + d);
    float4 x1 = *(float4*)(row + d + 4);
    float s = x0.x + x0.y + x0.z + x0.w + x1.x + x1.y + x1.z + x1.w;
#pragma unroll
    for (int off = 32; off > 0; off >>= 1) s += __shfl_xor(s, off, 64);
    float mean = s * (1.f / 512.f);
    float d0 = x0.x - mean, d1 = x0.y - mean, d2 = x0.z - mean, d3 = x0.w - mean;
    float d4 = x1.x - mean, d5 = x1.y - mean, d6 = x1.z - mean, d7 = x1.w - mean;
    float vs = d0 * d0 + d1 * d1 + d2 * d2 + d3 * d3
             + d4 * d4 + d5 * d5 + d6 * d6 + d7 * d7;
#pragma unroll
    for (int off = 32; off > 0; off >>= 1) vs += __shfl_xor(vs, off, 64);
    float rstd = rsqrtf(vs * (1.f / 512.f) + 1e-5f);
    float4 ga = ld4(lg, d, isf32), gb = ld4(lg, d + 4, isf32);
    float4 ba = ld4(lb, d, isf32), bb = ld4(lb, d + 4, isf32);
    float o0 = d0 * rstd * ga.x + ba.x;
    float o1 = d1 * rstd * ga.y + ba.y;
    float o2 = d2 * rstd * ga.z + ba.z;
    float o3 = d3 * rstd * ga.w + ba.w;
    float o4 = d4 * rstd * gb.x + bb.x;
    float o5 = d5 * rstd * gb.y + bb.y;
    float o6 = d6 * rstd * gb.z + bb.z;
    float o7 = d7 * rstd * gb.w + bb.w;
    *(float4*)(row + d)     = make_float4(o0, o1, o2, o3);
    *(float4*)(row + d + 4) = make_float4(o4, o5, o6, o7);
    float4 wa = ld4(gW, d, isf32), wb = ld4(gW, d + 4, isf32);
    float4 va = ld4(gW, 512 + d, isf32), vb = ld4(gW, 512 + d + 4, isf32);
    float s1 = o0 * wa.x + o1 * wa.y + o2 * wa.z + o3 * wa.w
             + o4 * wb.x + o5 * wb.y + o6 * wb.z + o7 * wb.w;
    float s2 = o0 * va.x + o1 * va.y + o2 * va.z + o3 * va.w
             + o4 * vb.x + o5 * vb.y + o6 * vb.z + o7 * vb.w;
#pragma unroll
    for (int off = 32; off > 0; off >>= 1) {
        s1 += __shfl_down(s1, off, 64);
        s2 += __shfl_down(s2, off, 64);
    }
    if (lane == 0) { g1[m] = s1; g2[m] = s2; }
}

// ============================================================================
// Fused tail (one block per batch): gate logits -> exact top-256 radix-select
// -> q-proj -> scores/softmax -> ctx.  Compute loops vectorized (float4) and
// unrolled so loads pipeline instead of chaining on the accumulator.
// ============================================================================
__global__ __launch_bounds__(256) void k_tail(const float* __restrict__ h,
                                              const float* __restrict__ g1,
                                              const float* __restrict__ g2,
                                              const void* __restrict__ qW,
                                              const void* __restrict__ qb,
                                              float* __restrict__ ctx,
                                              const int* __restrict__ dflag)
{
    const bool isf32 = (*dflag != 0);
    const int b = blockIdx.x, tid = threadIdx.x;
    const int lane = tid & 63, wv = tid >> 6;
    __shared__ unsigned keys[NT];      // 16 KB
    __shared__ float g2s[NT];          // 16 KB (reused as hlast later)
    __shared__ float qv[ND];
    __shared__ float sc[NSLOTS];
    __shared__ int   sidx[NSLOTS];
    __shared__ int   red[4];
    __shared__ float fred[4];
    __shared__ int   s_cnt;

    // ---- gate logits -> sortable keys ----
    const float* g2r = g2 + (size_t)b * NT;
    const float* g1r = g1 + (size_t)b * NT;
    for (int i = tid; i < NT; i += 256) g2s[i] = g2r[i];
    __syncthreads();
    for (int i = tid; i < NT; i += 256) {
        int cnt = min(NK, NT - 1 - i);
        float s = 0.f;
        for (int j = 1; j <= cnt; ++j) s += g2s[i + j];
        float gate = g1r[i] + ((cnt > 0) ? s / (float)cnt : 0.f);
        unsigned u = __float_as_uint(gate);
        u = (u & 0x80000000u) ? ~u : (u | 0x80000000u);
        keys[i] = u;
    }
    __syncthreads();

    // ---- radix select threshold ----
    unsigned sel = 0;
    for (int bit = 31; bit >= 0; --bit) {
        unsigned cand = sel | (1u << bit);
        int c = 0;
        for (int i = tid; i < NT; i += 256) c += (keys[i] >= cand) ? 1 : 0;
#pragma unroll
        for (int off = 32; off > 0; off >>= 1) c += __shfl_down(c, off, 64);
        if (lane == 0) red[wv] = c;
        __syncthreads();
        int total = red[0] + red[1] + red[2] + red[3];
        __syncthreads();
        if (total >= NSLOTS) sel = cand;
    }
    if (tid == 0) s_cnt = 0;
    __syncthreads();
    for (int i = tid; i < NT; i += 256)
        if (keys[i] > sel) sidx[atomicAdd(&s_cnt, 1)] = i;
    __syncthreads();
    const int base = s_cnt;
    int tc = 0;
    for (int i = tid; i < NT; i += 256) tc += (keys[i] == sel) ? 1 : 0;
#pragma unroll
    for (int off = 32; off > 0; off >>= 1) tc += __shfl_down(tc, off, 64);
    if (lane == 0) red[wv] = tc;
    __syncthreads();
    int tcnt = red[0] + red[1] + red[2] + red[3];
    if (tcnt == NSLOTS - base) {
        for (int i = tid; i < NT; i += 256)
            if (keys[i] == sel) sidx[atomicAdd(&s_cnt, 1)] = i;
    } else if (tid == 0) {   // rare: more ties than slots -> lowest indices
        int p = base;
        for (int i = 0; i < NT && p < NSLOTS; ++i)
            if (keys[i] == sel) sidx[p++] = i;
    }
    __syncthreads();

    // ---- q = h[b,T-1] @ qW + qb : 128 threads x 4 cols, float4 along j ----
    const float* hb = h + (size_t)b * NT * ND;
    const float* hlast = hb + (size_t)(NT - 1) * ND;
    float* hl = g2s;   // reuse
    hl[tid] = hlast[tid];
    hl[256 + tid] = hlast[256 + tid];
    __syncthreads();
    if (tid < 128) {
        const int j4 = tid * 4;
        float4 a = make_float4(ld1(qb, j4, isf32),     ld1(qb, j4 + 1, isf32),
                               ld1(qb, j4 + 2, isf32), ld1(qb, j4 + 3, isf32));
#pragma unroll 4
        for (int d = 0; d < ND; ++d) {
            float hv = hl[d];
            float4 w = ld4(qW, (size_t)d * ND + j4, isf32);
            a.x += hv * w.x; a.y += hv * w.y; a.z += hv * w.z; a.w += hv * w.w;
        }
        *(float4*)&qv[j4] = a;
    }
    __syncthreads();

    // ---- scores + softmax (256 slots <-> 256 threads) ----
    float s = 0.f;
    {
        const float* row = hb + (size_t)sidx[tid] * ND;
#pragma unroll 8
        for (int d = 0; d < ND; d += 4) {
            float4 hv = *(const float4*)(row + d);
            float4 qq = *(const float4*)(qv + d);
            s += hv.x * qq.x + hv.y * qq.y + hv.z * qq.z + hv.w * qq.w;
        }
    }
    float mx = s;
#pragma unroll
    for (int off = 32; off > 0; off >>= 1) mx = fmaxf(mx, __shfl_xor(mx, off, 64));
    if (lane == 0) fred[wv] = mx;
    __syncthreads();
    mx = fmaxf(fmaxf(fred[0], fred[1]), fmaxf(fred[2], fred[3]));
    __syncthreads();
    float e = expf(s - mx);
    sc[tid] = e;
    float se = e;
#pragma unroll
    for (int off = 32; off > 0; off >>= 1) se += __shfl_xor(se, off, 64);
    if (lane == 0) fred[wv] = se;
    __syncthreads();
    float inv = 1.f / (fred[0] + fred[1] + fred[2] + fred[3]);
    __syncthreads();

    // ---- ctx: 128 threads x 4 dims, coalesced float4 rows ----
    if (tid < 128) {
        const int d4 = tid * 4;
        float ax = 0.f, ay = 0.f, az = 0.f, aw = 0.f;
#pragma unroll 4
        for (int m = 0; m < NSLOTS; ++m) {
            const float* r = hb + (size_t)sidx[m] * ND + d4;
            float4 v = *(const float4*)r;
            float w = sc[m];
            ax += w * v.x; ay += w * v.y; az += w * v.z; aw += w * v.w;
        }
        float4 o = make_float4(ax * inv, ay * inv, az * inv, aw * inv);
        *(float4*)&ctx[b * ND + d4] = o;
    }
}

// ============================================================================
// out[b][v] = ctx[b] · out_W[:,v] + out_b[v]   (1 col/thread, d-loop unrolled)
// ============================================================================
__global__ __launch_bounds__(256) void k_out(const float* __restrict__ ctx,
                                             const void* __restrict__ outW,
                                             const void* __restrict__ outb,
                                             void* __restrict__ out,
                                             const int* __restrict__ dflag)
{
    const bool isf32 = (*dflag != 0);
    __shared__ float cs[NB * ND];
    const int tid = threadIdx.x;
    for (int i = tid; i < NB * ND; i += 256) cs[i] = ctx[i];
    __syncthreads();
    int v = blockIdx.x * 256 + tid;
    if (v >= NV) return;
    float acc[NB];
#pragma unroll
    for (int bb = 0; bb < NB; ++bb) acc[bb] = 0.f;
#pragma unroll 8
    for (int d = 0; d < ND; ++d) {
        float w = ld1(outW, (size_t)d * NV + v, isf32);
#pragma unroll
        for (int bb = 0; bb < NB; ++bb) acc[bb] += cs[bb * ND + d] * w;
    }
    float ob = ld1(outb, v, isf32);
#pragma unroll
    for (int bb = 0; bb < NB; ++bb) {
        float r = acc[bb] + ob;
        size_t o = (size_t)bb * NV + v;
        if (isf32) ((float*)out)[o] = r;
        else       ((u16*)out)[o]   = f2b(r);
    }
}

// ============================================================================
extern "C" void kernel_launch(void* const* d_in, const int* in_sizes, int n_in,
                              void* d_out, int out_size, void* d_ws, size_t ws_size,
                              hipStream_t stream)
{
    const int*  seq   = (const int*)d_in[0];
    const void* embed = d_in[1];
    const void* W1    = d_in[2];
    const void* b1    = d_in[3];
    const void* W2    = d_in[4];
    const void* b2v   = d_in[5];
    const void* lng   = d_in[6];
    const void* lnb   = d_in[7];
    const void* gateW = d_in[8];
    // d_in[9] = gate_b (constant shift, irrelevant for top-k ordering)
    const void* qW    = d_in[10];
    const void* qb    = d_in[11];
    const void* outW  = d_in[12];
    const void* outb  = d_in[13];

    // ---- ws layout (identical for both paths; round-3 proven capacity) ----
    float* ws   = (float*)d_ws;
    int*   flag = (int*)ws;                    // ws[0..3] (16B pad)
    float* g1   = ws + 4;                      // NM
    float* g2   = g1 + NM;                     // NM
    float* ctx  = g2 + NM;                     // NB*ND
    float* h    = ctx + NB * ND;               // NM*ND f32 (64 MiB)
    u16* A1hi   = (u16*)(h + (size_t)NM * ND); // NM*512 bf16 (generic path only)
    u16* A1lo   = A1hi + (size_t)NM * ND;
    u16* W1thi  = A1lo + (size_t)NM * ND;      // [1024][512] (1 MiB)
    u16* W1tlo  = W1thi + (size_t)1024 * 512;
    u16* W2thi  = W1tlo + (size_t)1024 * 512;  // [512][1024]
    u16* W2tlo  = W2thi + (size_t)1024 * 512;
    u16* t1hi   = W2tlo + (size_t)1024 * 512;  // [MC][1024] bf16 hi

    const size_t usedB = (size_t)((char*)t1hi - (char*)d_ws);
    int MC;
    if      (ws_size >= usedB + (size_t)32768 * 4096) MC = 32768;
    else if (ws_size >= usedB + (size_t)16384 * 4096) MC = 16384;
    else if (ws_size >= usedB + (size_t)8192  * 4096) MC = 8192;
    else                                              MC = 4096;
    u16* t1lo = t1hi + (size_t)MC * 1024;

    // host-side dtype check from W1 byte size (graph-safe: pure host branch).
    const bool hostBf16 = (n_in >= 14) && (in_sizes[2] == 512 * 1024 * 2);

    k_detect<<<1, 256, 0, stream>>>(W1, flag);
    k_splitWT<<<dim3(32, 16), 256, 0, stream>>>(W1, W1thi, W1tlo, 512, 1024, flag);
    k_splitWT<<<dim3(16, 32), 256, 0, stream>>>(W2, W2thi, W2tlo, 1024, 512, flag);

    if (hostBf16) {
        // fast path: A gathered straight from embed; t1 kept hi/lo (bit-identical)
        for (int m0g = 0; m0g < NM; m0g += MC) {
            k_bmfma<16, 8, true, true, 1><<<(MC / 128) * 8, 256, 0, stream>>>(
                (const u16*)embed, nullptr, seq, W1thi, (const u16*)b1,
                t1hi, t1lo, nullptr, nullptr, m0g);
            k_bmfma<32, 4, false, false, 2><<<(MC / 128) * 4, 256, 0, stream>>>(
                t1hi, t1lo, seq, W2thi, (const u16*)b2v,
                nullptr, nullptr, h, (const u16*)embed, m0g);
        }
    } else {
        k_splitA<<<NM / 4, 256, 0, stream>>>(seq, embed, A1hi, A1lo, flag);
        for (int m0g = 0; m0g < NM; m0g += MC) {
            k_mfma<16, 8, true><<<(MC / 128) * 8, 256, 0, stream>>>(
                A1hi + (size_t)m0g * ND, A1lo + (size_t)m0g * ND,
                W1thi, W1tlo, b1, t1hi, t1lo,
                nullptr, nullptr, nullptr, 0, flag);
            k_mfma<32, 4, false><<<(MC / 128) * 4, 256, 0, stream>>>(
                t1hi, t1lo, W2thi, W2tlo, b2v,
                nullptr, nullptr, h, seq, embed, m0g, flag);
        }
    }

    k_lng<<<NM / 4, 256, 0, stream>>>(h, lng, lnb, gateW, g1, g2, flag);
    k_tail<<<NB, 256, 0, stream>>>(h, g1, g2, qW, qb, ctx, flag);
    k_out<<<(NV + 255) / 256, 256, 0, stream>>>(ctx, outW, outb, d_out, flag);
}

// Round 5
// 673.045 us; speedup vs baseline: 2.5522x; 1.2555x over previous
//
#include <hip/hip_runtime.h>

typedef unsigned short u16;
typedef __attribute__((ext_vector_type(8))) short bf16x8;   // 8 bf16 = 4 VGPRs
typedef __attribute__((ext_vector_type(4))) float f32x4;

// ---- problem constants ----
constexpr int NV = 50257;   // vocab
constexpr int ND = 512;     // hidden
constexpr int NT = 4096;    // seq len
constexpr int NB = 8;       // batch
constexpr int NM = NB * NT; // 32768 tokens
constexpr int NSLOTS = 256;
constexpr int NK = 8;       // lookahead window

__device__ __forceinline__ float b2f(u16 u) { return __uint_as_float(((unsigned)u) << 16); }
__device__ __forceinline__ u16 f2b(float f) {
    unsigned u = __float_as_uint(f);
    u += 0x7FFFu + ((u >> 16) & 1u);   // round-to-nearest-even
    return (u16)(u >> 16);
}

// Dual-dtype element loads. isf32 is wave-uniform (device-detected flag).
__device__ __forceinline__ float ld1(const void* p, size_t i, bool isf32) {
    return isf32 ? ((const float*)p)[i] : b2f(((const u16*)p)[i]);
}
__device__ __forceinline__ float4 ld4(const void* p, size_t i, bool isf32) {
    if (isf32) return *(const float4*)((const float*)p + i);
    ushort4 v = *(const ushort4*)((const u16*)p + i);
    return make_float4(b2f(v.x), b2f(v.y), b2f(v.z), b2f(v.w));
}

// async global->LDS, 16B per lane (dest = wave-uniform base + lane*16)
__device__ __forceinline__ void gll16(const void* g, void* l) {
    __builtin_amdgcn_global_load_lds(
        (const __attribute__((address_space(1))) void*)g,
        (__attribute__((address_space(3))) void*)l, 16, 0, 0);
}

// ============================================================================
// Dtype detection: sample even-indexed u16s of W1 (512*1024 randn*0.02 elems).
// bf16 data -> exponent field in [100,130] ~100%; f32 -> ~12%.
// ============================================================================
__global__ __launch_bounds__(256) void k_detect(const void* w1, int* flag)
{
    __shared__ int red[256];
    const int tid = threadIdx.x;
    const u16* p = (const u16*)w1;
    int good = 0;
    for (int i = 0; i < 16; ++i) {
        u16 v = p[(size_t)(tid * 16 + i) * 2];   // even index
        int e = (v >> 7) & 0xFF;
        good += (e >= 100 && e <= 130) ? 1 : 0;
    }
    red[tid] = good;
    __syncthreads();
    for (int off = 128; off > 0; off >>= 1) {
        if (tid < off) red[tid] += red[tid + off];
        __syncthreads();
    }
    if (tid == 0) *flag = (red[0] < 2048) ? 1 : 0;   // <50% plausible => f32
}

// ============================================================================
// Streaming convert to bf16 (identity copy when input is already bf16).
// n8 = element count / 8.
// ============================================================================
__global__ __launch_bounds__(256) void k_cvt(const void* __restrict__ src,
                                             u16* __restrict__ dst, int n8,
                                             const int* __restrict__ dflag)
{
    const bool isf32 = (*dflag != 0);
    const int stride = gridDim.x * 256;
    for (int i = blockIdx.x * 256 + threadIdx.x; i < n8; i += stride) {
        size_t e = (size_t)i * 8;
        float4 a = ld4(src, e, isf32);
        float4 b = ld4(src, e + 4, isf32);
        *(ushort4*)&dst[e]     = make_ushort4(f2b(a.x), f2b(a.y), f2b(a.z), f2b(a.w));
        *(ushort4*)&dst[e + 4] = make_ushort4(f2b(b.x), f2b(b.y), f2b(b.z), f2b(b.w));
    }
}

// ============================================================================
// Transpose to bf16: src [R][C] (f32 or bf16) -> hiT [C][R] bf16 (RNE).
// ============================================================================
__global__ __launch_bounds__(256) void k_cvtWT(const void* __restrict__ src,
                                               u16* __restrict__ hiT,
                                               int R, int C,
                                               const int* __restrict__ dflag)
{
    const bool isf32 = (*dflag != 0);
    __shared__ float tile[32][33];
    const int tx = threadIdx.x & 31, ty = threadIdx.x >> 5;   // 32 x 8
    const int c0 = blockIdx.x * 32, r0 = blockIdx.y * 32;
#pragma unroll
    for (int k = 0; k < 4; ++k)
        tile[ty + 8 * k][tx] = ld1(src, (size_t)(r0 + ty + 8 * k) * C + c0 + tx, isf32);
    __syncthreads();
#pragma unroll
    for (int k = 0; k < 4; ++k)
        hiT[(size_t)(c0 + ty + 8 * k) * R + r0 + tx] = f2b(tile[tx][ty + 8 * k]);
}

// ============================================================================
// Pure-bf16 MFMA GEMM, m97 single-buffer structure, BK=64:
//   per K-step: { 8x global_load_lds -> __syncthreads -> 16 ds_read_b128 +
//                 32 MFMA per wave -> __syncthreads }.
// 32 KB LDS + ~110 VGPR -> ~4 blocks/CU; cross-block overlap hides latency
// (m97/m114: occupancy beats explicit depth-1 pipelining).
// C[128x128] = A[m][K] @ Bt[n][K]^T.  256 thr = 4 waves (2x2 x 64x64).
// LDS fragment order: chunk ch=(mt<<7)+(g<<4)+r holds (row=mt*16+r, k=g*8);
// lane l of wave reads chunk mt*128 + kh*64 + l -> ds_read_b128 at lane*16,
// conflict-free.  1-D grid, bijective XCD swizzle, N-tile fast (A L2-reuse).
// GATHER: A row r comes from ebf[seq[m0+r]] (embedding gather, pre-cvt bf16).
// OUTT1: relu(acc+bias) -> bf16 t1[m][1024].  else: acc+bias+embed residual
// (read at ORIGINAL dtype: exact f32 residual for f32 inputs) -> f32 h.
// ============================================================================
template<int KSTEPS, int NTILES, bool GATHER, bool OUTT1>
__global__ __launch_bounds__(256) void k_bmfma(
    const u16* __restrict__ A,       // bf16 [rows][K] (ebf or t1)
    const int* __restrict__ seqg,
    const u16* __restrict__ Bt,      // bf16 [N][K]
    const u16* __restrict__ biasb,   // bf16 [N]
    u16* __restrict__ Ct1,
    float* __restrict__ Cf,
    const void* __restrict__ embed,  // residual source, original dtype
    int mG0, const int* __restrict__ dflag)
{
    constexpr int K = KSTEPS * 64;
    const bool isf32 = (*dflag != 0);
    __shared__ __align__(16) u16 lds[16384];   // A 16KB | B 16KB
    __shared__ int sSeq[128];
    const int tid = threadIdx.x;

    // bijective XCD swizzle (gridDim.x % 8 == 0)
    const int lin = blockIdx.x;
    const int qx = gridDim.x >> 3;
    const int wg = (lin & 7) * qx + (lin >> 3);
    const int m0 = (wg / NTILES) * 128;   // chunk-local
    const int n0 = (wg % NTILES) * 128;

    const int wid = tid >> 6, lane = tid & 63;
    const int wm = wid >> 1, wn = wid & 1;

    if (tid < 128) sSeq[tid] = seqg[mG0 + m0 + tid];
    __syncthreads();

    // staging source bases: 4 A-chunk rounds + 4 B-chunk rounds per K-step
    size_t aSrc[4], bSrc[4];
#pragma unroll
    for (int c = 0; c < 4; ++c) {
        int ch = c * 256 + tid;
        int r  = ((ch >> 7) << 4) + (ch & 15);
        int kg = ((ch >> 4) & 7) * 8;
        aSrc[c] = (GATHER ? (size_t)sSeq[r] : (size_t)(m0 + r)) * K + kg;
        bSrc[c] = (size_t)(n0 + r) * K + kg;
    }

    f32x4 acc[4][4];
#pragma unroll
    for (int i = 0; i < 4; ++i)
#pragma unroll
        for (int j = 0; j < 4; ++j) {
            acc[i][j][0] = 0.f; acc[i][j][1] = 0.f;
            acc[i][j][2] = 0.f; acc[i][j][3] = 0.f;
        }

    u16* sA = lds + tid * 8;
    u16* sB = lds + 8192 + tid * 8;
    const u16* fAb = lds + (wm * 512 + lane) * 8;
    const u16* fBb = lds + 8192 + (wn * 512 + lane) * 8;

    for (int ks = 0; ks < KSTEPS; ++ks) {
        const int ko = ks * 64;
#pragma unroll
        for (int c = 0; c < 4; ++c) gll16(A + aSrc[c] + ko, sA + c * 2048);
#pragma unroll
        for (int c = 0; c < 4; ++c) gll16(Bt + bSrc[c] + ko, sB + c * 2048);
        __syncthreads();   // drains vmcnt: staged tile visible
#pragma unroll
        for (int kh = 0; kh < 2; ++kh) {
            const u16* fA = fAb + kh * 512;
            const u16* fB = fBb + kh * 512;
            bf16x8 ah[4], bh[4];
#pragma unroll
            for (int i = 0; i < 4; ++i) ah[i] = *(const bf16x8*)(fA + i * 1024);
#pragma unroll
            for (int j = 0; j < 4; ++j) bh[j] = *(const bf16x8*)(fB + j * 1024);
#pragma unroll
            for (int j = 0; j < 4; ++j)
#pragma unroll
                for (int i = 0; i < 4; ++i)
                    acc[i][j] = __builtin_amdgcn_mfma_f32_16x16x32_bf16(ah[i], bh[j], acc[i][j], 0, 0, 0);
        }
        __syncthreads();   // LDS free for next stage
    }

    // ---- epilogue. C/D layout: col = lane&15, row = (lane>>4)*4 + reg ----
    const int lr = (lane >> 4) * 4;
    const int lc = lane & 15;
    if (OUTT1) {
#pragma unroll
        for (int j = 0; j < 4; ++j) {
            int col = n0 + wn * 64 + j * 16 + lc;
            float bv = b2f(biasb[col]);
#pragma unroll
            for (int i = 0; i < 4; ++i) {
                int row = m0 + wm * 64 + i * 16 + lr;   // chunk-local t1 row
#pragma unroll
                for (int r = 0; r < 4; ++r)
                    Ct1[(size_t)(row + r) * 1024 + col] =
                        f2b(fmaxf(acc[i][j][r] + bv, 0.f));
            }
        }
    } else {
#pragma unroll
        for (int j = 0; j < 4; ++j) {
            int col = n0 + wn * 64 + j * 16 + lc;
            float bv = b2f(biasb[col]);
#pragma unroll
            for (int i = 0; i < 4; ++i) {
                int br = wm * 64 + i * 16 + lr;
#pragma unroll
                for (int r = 0; r < 4; ++r) {
                    float v = acc[i][j][r] + bv
                            + ld1(embed, (size_t)sSeq[br + r] * ND + col, isf32);
                    Cf[(size_t)(mG0 + m0 + br + r) * ND + col] = v;
                }
            }
        }
    }
}

// ============================================================================
// Fused LayerNorm + gate partial dots, one wave per row, barrier-free.
// ============================================================================
__global__ __launch_bounds__(256) void k_lng(float* __restrict__ h,
                                             const void* __restrict__ lg,
                                             const void* __restrict__ lb,
                                             const void* __restrict__ gW,
                                             float* __restrict__ g1,
                                             float* __restrict__ g2,
                                             const int* __restrict__ dflag)
{
    const bool isf32 = (*dflag != 0);
    const int lane = threadIdx.x & 63;
    const int m = blockIdx.x * 4 + (threadIdx.x >> 6);
    float* row = h + (size_t)m * ND;
    const int d = lane * 8;
    float4 x0 = *(float4*)(row + d);
    float4 x1 = *(float4*)(row + d + 4);
    float s = x0.x + x0.y + x0.z + x0.w + x1.x + x1.y + x1.z + x1.w;
#pragma unroll
    for (int off = 32; off > 0; off >>= 1) s += __shfl_xor(s, off, 64);
    float mean = s * (1.f / 512.f);
    float d0 = x0.x - mean, d1 = x0.y - mean, d2 = x0.z - mean, d3 = x0.w - mean;
    float d4 = x1.x - mean, d5 = x1.y - mean, d6 = x1.z - mean, d7 = x1.w - mean;
    float vs = d0 * d0 + d1 * d1 + d2 * d2 + d3 * d3
             + d4 * d4 + d5 * d5 + d6 * d6 + d7 * d7;
#pragma unroll
    for (int off = 32; off > 0; off >>= 1) vs += __shfl_xor(vs, off, 64);
    float rstd = rsqrtf(vs * (1.f / 512.f) + 1e-5f);
    float4 ga = ld4(lg, d, isf32), gb = ld4(lg, d + 4, isf32);
    float4 ba = ld4(lb, d, isf32), bb = ld4(lb, d + 4, isf32);
    float o0 = d0 * rstd * ga.x + ba.x;
    float o1 = d1 * rstd * ga.y + ba.y;
    float o2 = d2 * rstd * ga.z + ba.z;
    float o3 = d3 * rstd * ga.w + ba.w;
    float o4 = d4 * rstd * gb.x + bb.x;
    float o5 = d5 * rstd * gb.y + bb.y;
    float o6 = d6 * rstd * gb.z + bb.z;
    float o7 = d7 * rstd * gb.w + bb.w;
    *(float4*)(row + d)     = make_float4(o0, o1, o2, o3);
    *(float4*)(row + d + 4) = make_float4(o4, o5, o6, o7);
    float4 wa = ld4(gW, d, isf32), wb = ld4(gW, d + 4, isf32);
    float4 va = ld4(gW, 512 + d, isf32), vb = ld4(gW, 512 + d + 4, isf32);
    float s1 = o0 * wa.x + o1 * wa.y + o2 * wa.z + o3 * wa.w
             + o4 * wb.x + o5 * wb.y + o6 * wb.z + o7 * wb.w;
    float s2 = o0 * va.x + o1 * va.y + o2 * va.z + o3 * va.w
             + o4 * vb.x + o5 * vb.y + o6 * vb.z + o7 * vb.w;
#pragma unroll
    for (int off = 32; off > 0; off >>= 1) {
        s1 += __shfl_down(s1, off, 64);
        s2 += __shfl_down(s2, off, 64);
    }
    if (lane == 0) { g1[m] = s1; g2[m] = s2; }
}

// ============================================================================
// Fused tail (one block per batch): gate logits -> exact top-256 radix-select
// -> q-proj -> scores/softmax -> ctx.
// ============================================================================
__global__ __launch_bounds__(256) void k_tail(const float* __restrict__ h,
                                              const float* __restrict__ g1,
                                              const float* __restrict__ g2,
                                              const void* __restrict__ qW,
                                              const void* __restrict__ qb,
                                              float* __restrict__ ctx,
                                              const int* __restrict__ dflag)
{
    const bool isf32 = (*dflag != 0);
    const int b = blockIdx.x, tid = threadIdx.x;
    const int lane = tid & 63, wv = tid >> 6;
    __shared__ unsigned keys[NT];      // 16 KB
    __shared__ float g2s[NT];          // 16 KB (reused as hlast later)
    __shared__ float qv[ND];
    __shared__ float sc[NSLOTS];
    __shared__ int   sidx[NSLOTS];
    __shared__ int   red[4];
    __shared__ float fred[4];
    __shared__ int   s_cnt;

    // ---- gate logits -> sortable keys ----
    const float* g2r = g2 + (size_t)b * NT;
    const float* g1r = g1 + (size_t)b * NT;
    for (int i = tid; i < NT; i += 256) g2s[i] = g2r[i];
    __syncthreads();
    for (int i = tid; i < NT; i += 256) {
        int cnt = min(NK, NT - 1 - i);
        float s = 0.f;
        for (int j = 1; j <= cnt; ++j) s += g2s[i + j];
        float gate = g1r[i] + ((cnt > 0) ? s / (float)cnt : 0.f);
        unsigned u = __float_as_uint(gate);
        u = (u & 0x80000000u) ? ~u : (u | 0x80000000u);
        keys[i] = u;
    }
    __syncthreads();

    // ---- radix select threshold ----
    unsigned sel = 0;
    for (int bit = 31; bit >= 0; --bit) {
        unsigned cand = sel | (1u << bit);
        int c = 0;
        for (int i = tid; i < NT; i += 256) c += (keys[i] >= cand) ? 1 : 0;
#pragma unroll
        for (int off = 32; off > 0; off >>= 1) c += __shfl_down(c, off, 64);
        if (lane == 0) red[wv] = c;
        __syncthreads();
        int total = red[0] + red[1] + red[2] + red[3];
        __syncthreads();
        if (total >= NSLOTS) sel = cand;
    }
    if (tid == 0) s_cnt = 0;
    __syncthreads();
    for (int i = tid; i < NT; i += 256)
        if (keys[i] > sel) sidx[atomicAdd(&s_cnt, 1)] = i;
    __syncthreads();
    const int base = s_cnt;
    int tc = 0;
    for (int i = tid; i < NT; i += 256) tc += (keys[i] == sel) ? 1 : 0;
#pragma unroll
    for (int off = 32; off > 0; off >>= 1) tc += __shfl_down(tc, off, 64);
    if (lane == 0) red[wv] = tc;
    __syncthreads();
    int tcnt = red[0] + red[1] + red[2] + red[3];
    if (tcnt == NSLOTS - base) {
        for (int i = tid; i < NT; i += 256)
            if (keys[i] == sel) sidx[atomicAdd(&s_cnt, 1)] = i;
    } else if (tid == 0) {   // rare: more ties than slots -> lowest indices
        int p = base;
        for (int i = 0; i < NT && p < NSLOTS; ++i)
            if (keys[i] == sel) sidx[p++] = i;
    }
    __syncthreads();

    // ---- q = h[b,T-1] @ qW + qb : 128 threads x 4 cols ----
    const float* hb = h + (size_t)b * NT * ND;
    const float* hlast = hb + (size_t)(NT - 1) * ND;
    float* hl = g2s;   // reuse
    hl[tid] = hlast[tid];
    hl[256 + tid] = hlast[256 + tid];
    __syncthreads();
    if (tid < 128) {
        const int j4 = tid * 4;
        float4 a = make_float4(ld1(qb, j4, isf32),     ld1(qb, j4 + 1, isf32),
                               ld1(qb, j4 + 2, isf32), ld1(qb, j4 + 3, isf32));
#pragma unroll 4
        for (int d = 0; d < ND; ++d) {
            float hv = hl[d];
            float4 w = ld4(qW, (size_t)d * ND + j4, isf32);
            a.x += hv * w.x; a.y += hv * w.y; a.z += hv * w.z; a.w += hv * w.w;
        }
        *(float4*)&qv[j4] = a;
    }
    __syncthreads();

    // ---- scores + softmax (256 slots <-> 256 threads) ----
    float s = 0.f;
    {
        const float* row = hb + (size_t)sidx[tid] * ND;
#pragma unroll 8
        for (int d = 0; d < ND; d += 4) {
            float4 hv = *(const float4*)(row + d);
            float4 qq = *(const float4*)(qv + d);
            s += hv.x * qq.x + hv.y * qq.y + hv.z * qq.z + hv.w * qq.w;
        }
    }
    float mx = s;
#pragma unroll
    for (int off = 32; off > 0; off >>= 1) mx = fmaxf(mx, __shfl_xor(mx, off, 64));
    if (lane == 0) fred[wv] = mx;
    __syncthreads();
    mx = fmaxf(fmaxf(fred[0], fred[1]), fmaxf(fred[2], fred[3]));
    __syncthreads();
    float e = expf(s - mx);
    sc[tid] = e;
    float se = e;
#pragma unroll
    for (int off = 32; off > 0; off >>= 1) se += __shfl_xor(se, off, 64);
    if (lane == 0) fred[wv] = se;
    __syncthreads();
    float inv = 1.f / (fred[0] + fred[1] + fred[2] + fred[3]);
    __syncthreads();

    // ---- ctx: 128 threads x 4 dims ----
    if (tid < 128) {
        const int d4 = tid * 4;
        float ax = 0.f, ay = 0.f, az = 0.f, aw = 0.f;
#pragma unroll 4
        for (int m = 0; m < NSLOTS; ++m) {
            const float* r = hb + (size_t)sidx[m] * ND + d4;
            float4 v = *(const float4*)r;
            float w = sc[m];
            ax += w * v.x; ay += w * v.y; az += w * v.z; aw += w * v.w;
        }
        *(float4*)&ctx[b * ND + d4] = make_float4(ax * inv, ay * inv, az * inv, aw * inv);
    }
}

// ============================================================================
// out[b][v] = ctx[b] · out_W[:,v] + out_b[v]   (1 col/thread)
// ============================================================================
__global__ __launch_bounds__(256) void k_out(const float* __restrict__ ctx,
                                             const void* __restrict__ outW,
                                             const void* __restrict__ outb,
                                             void* __restrict__ out,
                                             const int* __restrict__ dflag)
{
    const bool isf32 = (*dflag != 0);
    __shared__ float cs[NB * ND];
    const int tid = threadIdx.x;
    for (int i = tid; i < NB * ND; i += 256) cs[i] = ctx[i];
    __syncthreads();
    int v = blockIdx.x * 256 + tid;
    if (v >= NV) return;
    float acc[NB];
#pragma unroll
    for (int bb = 0; bb < NB; ++bb) acc[bb] = 0.f;
#pragma unroll 8
    for (int d = 0; d < ND; ++d) {
        float w = ld1(outW, (size_t)d * NV + v, isf32);
#pragma unroll
        for (int bb = 0; bb < NB; ++bb) acc[bb] += cs[bb * ND + d] * w;
    }
    float ob = ld1(outb, v, isf32);
#pragma unroll
    for (int bb = 0; bb < NB; ++bb) {
        float r = acc[bb] + ob;
        size_t o = (size_t)bb * NV + v;
        if (isf32) ((float*)out)[o] = r;
        else       ((u16*)out)[o]   = f2b(r);
    }
}

// ============================================================================
extern "C" void kernel_launch(void* const* d_in, const int* in_sizes, int n_in,
                              void* d_out, int out_size, void* d_ws, size_t ws_size,
                              hipStream_t stream)
{
    const int*  seq   = (const int*)d_in[0];
    const void* embed = d_in[1];
    const void* W1    = d_in[2];
    const void* b1    = d_in[3];
    const void* W2    = d_in[4];
    const void* b2v   = d_in[5];
    const void* lng   = d_in[6];
    const void* lnb   = d_in[7];
    const void* gateW = d_in[8];
    // d_in[9] = gate_b (constant shift, irrelevant for top-k ordering)
    const void* qW    = d_in[10];
    const void* qb    = d_in[11];
    const void* outW  = d_in[12];
    const void* outb  = d_in[13];

    // ---- ws layout ----
    float* ws   = (float*)d_ws;
    int*   flag = (int*)ws;                    // ws[0..3] (16B pad)
    float* g1   = ws + 4;                      // NM
    float* g2   = g1 + NM;                     // NM
    float* ctx  = g2 + NM;                     // NB*ND
    float* h    = ctx + NB * ND;               // NM*ND f32 (64 MiB)
    u16* ebf    = (u16*)(h + (size_t)NM * ND); // NV*ND bf16 (51.5 MiB)
    u16* W1t    = ebf + (size_t)NV * ND;       // [1024][512] bf16 (1 MiB)
    u16* W2t    = W1t + (size_t)1024 * 512;    // [512][1024] bf16 (1 MiB)
    u16* b1b    = W2t + (size_t)512 * 1024;    // 1024 bf16
    u16* b2b    = b1b + 1024;                  // 512 bf16
    u16* t1     = b2b + 512;                   // [MC][1024] bf16

    // ws-adaptive M-chunk (t1 = MC*2048 B). Host branch on ws_size only.
    const size_t usedB = (size_t)((char*)t1 - (char*)d_ws);
    int MC;
    if      (ws_size >= usedB + (size_t)32768 * 2048) MC = 32768;
    else if (ws_size >= usedB + (size_t)16384 * 2048) MC = 16384;
    else if (ws_size >= usedB + (size_t)8192  * 2048) MC = 8192;
    else                                              MC = 4096;

    k_detect<<<1, 256, 0, stream>>>(W1, flag);
    // pre-convert operands to bf16 (identity copy when input already bf16)
    k_cvt<<<2048, 256, 0, stream>>>(embed, ebf, NV * ND / 8, flag);
    k_cvt<<<1, 256, 0, stream>>>(b1, b1b, 1024 / 8, flag);
    k_cvt<<<1, 256, 0, stream>>>(b2v, b2b, 512 / 8, flag);
    k_cvtWT<<<dim3(32, 16), 256, 0, stream>>>(W1, W1t, 512, 1024, flag);
    k_cvtWT<<<dim3(16, 32), 256, 0, stream>>>(W2, W2t, 1024, 512, flag);

    for (int m0g = 0; m0g < NM; m0g += MC) {
        // GEMM1: t1 = relu(bf16(embed[seq]) @ W1 + b1)    K=512 -> 8 K-steps
        k_bmfma<8, 8, true, true><<<(MC / 128) * 8, 256, 0, stream>>>(
            ebf, seq, W1t, b1b, t1, nullptr, embed, m0g, flag);
        // GEMM2: h = t1 @ W2 + b2 + embed[seq] (residual at original dtype)
        k_bmfma<16, 4, false, false><<<(MC / 128) * 4, 256, 0, stream>>>(
            t1, seq, W2t, b2b, nullptr, h, embed, m0g, flag);
    }

    k_lng<<<NM / 4, 256, 0, stream>>>(h, lng, lnb, gateW, g1, g2, flag);
    k_tail<<<NB, 256, 0, stream>>>(h, g1, g2, qW, qb, ctx, flag);
    k_out<<<(NV + 255) / 256, 256, 0, stream>>>(ctx, outW, outb, d_out, flag);
}

// Round 6
// 603.797 us; speedup vs baseline: 2.8449x; 1.1147x over previous
//
#include <hip/hip_runtime.h>

typedef unsigned short u16;
typedef __attribute__((ext_vector_type(8))) short bf16x8;   // 8 bf16 = 4 VGPRs
typedef __attribute__((ext_vector_type(4))) float f32x4;

// ---- problem constants ----
constexpr int NV = 50257;   // vocab
constexpr int ND = 512;     // hidden
constexpr int NT = 4096;    // seq len
constexpr int NB = 8;       // batch
constexpr int NM = NB * NT; // 32768 tokens
constexpr int NSLOTS = 256;
constexpr int NK = 8;       // lookahead window

__device__ __forceinline__ float b2f(u16 u) { return __uint_as_float(((unsigned)u) << 16); }
__device__ __forceinline__ u16 f2b(float f) {
    unsigned u = __float_as_uint(f);
    u += 0x7FFFu + ((u >> 16) & 1u);   // round-to-nearest-even
    return (u16)(u >> 16);
}

// Dual-dtype element loads. isf32 is wave-uniform (device-detected flag).
__device__ __forceinline__ float ld1(const void* p, size_t i, bool isf32) {
    return isf32 ? ((const float*)p)[i] : b2f(((const u16*)p)[i]);
}
__device__ __forceinline__ float4 ld4(const void* p, size_t i, bool isf32) {
    if (isf32) return *(const float4*)((const float*)p + i);
    ushort4 v = *(const ushort4*)((const u16*)p + i);
    return make_float4(b2f(v.x), b2f(v.y), b2f(v.z), b2f(v.w));
}

// async global->LDS, 16B per lane (dest = wave-uniform base + lane*16)
__device__ __forceinline__ void gll16(const void* g, void* l) {
    __builtin_amdgcn_global_load_lds(
        (const __attribute__((address_space(1))) void*)g,
        (__attribute__((address_space(3))) void*)l, 16, 0, 0);
}

// ============================================================================
// Dtype detection: sample even-indexed u16s of W1 (512*1024 randn*0.02 elems).
// bf16 data -> exponent field in [100,130] ~100%; f32 -> ~12%.
// ============================================================================
__global__ __launch_bounds__(256) void k_detect(const void* w1, int* flag)
{
    __shared__ int red[256];
    const int tid = threadIdx.x;
    const u16* p = (const u16*)w1;
    int good = 0;
    for (int i = 0; i < 16; ++i) {
        u16 v = p[(size_t)(tid * 16 + i) * 2];   // even index
        int e = (v >> 7) & 0xFF;
        good += (e >= 100 && e <= 130) ? 1 : 0;
    }
    red[tid] = good;
    __syncthreads();
    for (int off = 128; off > 0; off >>= 1) {
        if (tid < off) red[tid] += red[tid + off];
        __syncthreads();
    }
    if (tid == 0) *flag = (red[0] < 2048) ? 1 : 0;   // <50% plausible => f32
}

// ============================================================================
// Streaming convert to bf16 (identity copy when input is already bf16).
// n8 = element count / 8.
// ============================================================================
__global__ __launch_bounds__(256) void k_cvt(const void* __restrict__ src,
                                             u16* __restrict__ dst, int n8,
                                             const int* __restrict__ dflag)
{
    const bool isf32 = (*dflag != 0);
    const int stride = gridDim.x * 256;
    for (int i = blockIdx.x * 256 + threadIdx.x; i < n8; i += stride) {
        size_t e = (size_t)i * 8;
        float4 a = ld4(src, e, isf32);
        float4 b = ld4(src, e + 4, isf32);
        *(ushort4*)&dst[e]     = make_ushort4(f2b(a.x), f2b(a.y), f2b(a.z), f2b(a.w));
        *(ushort4*)&dst[e + 4] = make_ushort4(f2b(b.x), f2b(b.y), f2b(b.z), f2b(b.w));
    }
}

// ============================================================================
// Transpose to bf16: src [R][C] (f32 or bf16) -> hiT [C][R] bf16 (RNE).
// ============================================================================
__global__ __launch_bounds__(256) void k_cvtWT(const void* __restrict__ src,
                                               u16* __restrict__ hiT,
                                               int R, int C,
                                               const int* __restrict__ dflag)
{
    const bool isf32 = (*dflag != 0);
    __shared__ float tile[32][33];
    const int tx = threadIdx.x & 31, ty = threadIdx.x >> 5;   // 32 x 8
    const int c0 = blockIdx.x * 32, r0 = blockIdx.y * 32;
#pragma unroll
    for (int k = 0; k < 4; ++k)
        tile[ty + 8 * k][tx] = ld1(src, (size_t)(r0 + ty + 8 * k) * C + c0 + tx, isf32);
    __syncthreads();
#pragma unroll
    for (int k = 0; k < 4; ++k)
        hiT[(size_t)(c0 + ty + 8 * k) * R + r0 + tx] = f2b(tile[tx][ty + 8 * k]);
}

// ============================================================================
// Pure-bf16 MFMA GEMM, m97 single-buffer structure, BK=64 (round-5 proven).
// ============================================================================
template<int KSTEPS, int NTILES, bool GATHER, bool OUTT1>
__global__ __launch_bounds__(256) void k_bmfma(
    const u16* __restrict__ A,       // bf16 [rows][K] (ebf or t1)
    const int* __restrict__ seqg,
    const u16* __restrict__ Bt,      // bf16 [N][K]
    const u16* __restrict__ biasb,   // bf16 [N]
    u16* __restrict__ Ct1,
    float* __restrict__ Cf,
    const void* __restrict__ embed,  // residual source, original dtype
    int mG0, const int* __restrict__ dflag)
{
    constexpr int K = KSTEPS * 64;
    const bool isf32 = (*dflag != 0);
    __shared__ __align__(16) u16 lds[16384];   // A 16KB | B 16KB
    __shared__ int sSeq[128];
    const int tid = threadIdx.x;

    // bijective XCD swizzle (gridDim.x % 8 == 0)
    const int lin = blockIdx.x;
    const int qx = gridDim.x >> 3;
    const int wg = (lin & 7) * qx + (lin >> 3);
    const int m0 = (wg / NTILES) * 128;   // chunk-local
    const int n0 = (wg % NTILES) * 128;

    const int wid = tid >> 6, lane = tid & 63;
    const int wm = wid >> 1, wn = wid & 1;

    if (tid < 128) sSeq[tid] = seqg[mG0 + m0 + tid];
    __syncthreads();

    // staging source bases: 4 A-chunk rounds + 4 B-chunk rounds per K-step
    size_t aSrc[4], bSrc[4];
#pragma unroll
    for (int c = 0; c < 4; ++c) {
        int ch = c * 256 + tid;
        int r  = ((ch >> 7) << 4) + (ch & 15);
        int kg = ((ch >> 4) & 7) * 8;
        aSrc[c] = (GATHER ? (size_t)sSeq[r] : (size_t)(m0 + r)) * K + kg;
        bSrc[c] = (size_t)(n0 + r) * K + kg;
    }

    f32x4 acc[4][4];
#pragma unroll
    for (int i = 0; i < 4; ++i)
#pragma unroll
        for (int j = 0; j < 4; ++j) {
            acc[i][j][0] = 0.f; acc[i][j][1] = 0.f;
            acc[i][j][2] = 0.f; acc[i][j][3] = 0.f;
        }

    u16* sA = lds + tid * 8;
    u16* sB = lds + 8192 + tid * 8;
    const u16* fAb = lds + (wm * 512 + lane) * 8;
    const u16* fBb = lds + 8192 + (wn * 512 + lane) * 8;

    for (int ks = 0; ks < KSTEPS; ++ks) {
        const int ko = ks * 64;
#pragma unroll
        for (int c = 0; c < 4; ++c) gll16(A + aSrc[c] + ko, sA + c * 2048);
#pragma unroll
        for (int c = 0; c < 4; ++c) gll16(Bt + bSrc[c] + ko, sB + c * 2048);
        __syncthreads();   // drains vmcnt: staged tile visible
#pragma unroll
        for (int kh = 0; kh < 2; ++kh) {
            const u16* fA = fAb + kh * 512;
            const u16* fB = fBb + kh * 512;
            bf16x8 ah[4], bh[4];
#pragma unroll
            for (int i = 0; i < 4; ++i) ah[i] = *(const bf16x8*)(fA + i * 1024);
#pragma unroll
            for (int j = 0; j < 4; ++j) bh[j] = *(const bf16x8*)(fB + j * 1024);
#pragma unroll
            for (int j = 0; j < 4; ++j)
#pragma unroll
                for (int i = 0; i < 4; ++i)
                    acc[i][j] = __builtin_amdgcn_mfma_f32_16x16x32_bf16(ah[i], bh[j], acc[i][j], 0, 0, 0);
        }
        __syncthreads();   // LDS free for next stage
    }

    // ---- epilogue. C/D layout: col = lane&15, row = (lane>>4)*4 + reg ----
    const int lr = (lane >> 4) * 4;
    const int lc = lane & 15;
    if (OUTT1) {
#pragma unroll
        for (int j = 0; j < 4; ++j) {
            int col = n0 + wn * 64 + j * 16 + lc;
            float bv = b2f(biasb[col]);
#pragma unroll
            for (int i = 0; i < 4; ++i) {
                int row = m0 + wm * 64 + i * 16 + lr;   // chunk-local t1 row
#pragma unroll
                for (int r = 0; r < 4; ++r)
                    Ct1[(size_t)(row + r) * 1024 + col] =
                        f2b(fmaxf(acc[i][j][r] + bv, 0.f));
            }
        }
    } else {
#pragma unroll
        for (int j = 0; j < 4; ++j) {
            int col = n0 + wn * 64 + j * 16 + lc;
            float bv = b2f(biasb[col]);
#pragma unroll
            for (int i = 0; i < 4; ++i) {
                int br = wm * 64 + i * 16 + lr;
#pragma unroll
                for (int r = 0; r < 4; ++r) {
                    float v = acc[i][j][r] + bv
                            + ld1(embed, (size_t)sSeq[br + r] * ND + col, isf32);
                    Cf[(size_t)(mG0 + m0 + br + r) * ND + col] = v;
                }
            }
        }
    }
}

// ============================================================================
// Fused LayerNorm + gate partial dots, one wave per row, barrier-free.
// ============================================================================
__global__ __launch_bounds__(256) void k_lng(float* __restrict__ h,
                                             const void* __restrict__ lg,
                                             const void* __restrict__ lb,
                                             const void* __restrict__ gW,
                                             float* __restrict__ g1,
                                             float* __restrict__ g2,
                                             const int* __restrict__ dflag)
{
    const bool isf32 = (*dflag != 0);
    const int lane = threadIdx.x & 63;
    const int m = blockIdx.x * 4 + (threadIdx.x >> 6);
    float* row = h + (size_t)m * ND;
    const int d = lane * 8;
    float4 x0 = *(float4*)(row + d);
    float4 x1 = *(float4*)(row + d + 4);
    float s = x0.x + x0.y + x0.z + x0.w + x1.x + x1.y + x1.z + x1.w;
#pragma unroll
    for (int off = 32; off > 0; off >>= 1) s += __shfl_xor(s, off, 64);
    float mean = s * (1.f / 512.f);
    float d0 = x0.x - mean, d1 = x0.y - mean, d2 = x0.z - mean, d3 = x0.w - mean;
    float d4 = x1.x - mean, d5 = x1.y - mean, d6 = x1.z - mean, d7 = x1.w - mean;
    float vs = d0 * d0 + d1 * d1 + d2 * d2 + d3 * d3
             + d4 * d4 + d5 * d5 + d6 * d6 + d7 * d7;
#pragma unroll
    for (int off = 32; off > 0; off >>= 1) vs += __shfl_xor(vs, off, 64);
    float rstd = rsqrtf(vs * (1.f / 512.f) + 1e-5f);
    float4 ga = ld4(lg, d, isf32), gb = ld4(lg, d + 4, isf32);
    float4 ba = ld4(lb, d, isf32), bb = ld4(lb, d + 4, isf32);
    float o0 = d0 * rstd * ga.x + ba.x;
    float o1 = d1 * rstd * ga.y + ba.y;
    float o2 = d2 * rstd * ga.z + ba.z;
    float o3 = d3 * rstd * ga.w + ba.w;
    float o4 = d4 * rstd * gb.x + bb.x;
    float o5 = d5 * rstd * gb.y + bb.y;
    float o6 = d6 * rstd * gb.z + bb.z;
    float o7 = d7 * rstd * gb.w + bb.w;
    *(float4*)(row + d)     = make_float4(o0, o1, o2, o3);
    *(float4*)(row + d + 4) = make_float4(o4, o5, o6, o7);
    float4 wa = ld4(gW, d, isf32), wb = ld4(gW, d + 4, isf32);
    float4 va = ld4(gW, 512 + d, isf32), vb = ld4(gW, 512 + d + 4, isf32);
    float s1 = o0 * wa.x + o1 * wa.y + o2 * wa.z + o3 * wa.w
             + o4 * wb.x + o5 * wb.y + o6 * wb.z + o7 * wb.w;
    float s2 = o0 * va.x + o1 * va.y + o2 * va.z + o3 * va.w
             + o4 * vb.x + o5 * vb.y + o6 * vb.z + o7 * vb.w;
#pragma unroll
    for (int off = 32; off > 0; off >>= 1) {
        s1 += __shfl_down(s1, off, 64);
        s2 += __shfl_down(s2, off, 64);
    }
    if (lane == 0) { g1[m] = s1; g2[m] = s2; }
}

// ============================================================================
// q[b] = h[b,T-1] @ qW + qb.  64 blocks = 8 batches x 8 col-groups;
// 256 thr = 64 cols x 4 d-groups (128 d each), LDS partial reduce.
// Short load chains + 64-block parallelism: latency-bound -> ~6 us.
// ============================================================================
__global__ __launch_bounds__(256) void k_q(const float* __restrict__ h,
                                           const void* __restrict__ qW,
                                           const void* __restrict__ qb,
                                           float* __restrict__ qo,
                                           const int* __restrict__ dflag)
{
    const bool isf32 = (*dflag != 0);
    const int b = blockIdx.x >> 3, cg = blockIdx.x & 7;
    const int tid = threadIdx.x;
    const int lane = tid & 63, dg = tid >> 6;
    __shared__ float hl[ND];
    __shared__ float part[4][64];
    const float* row = h + ((size_t)b * NT + (NT - 1)) * ND;
    hl[tid] = row[tid];
    hl[256 + tid] = row[256 + tid];
    __syncthreads();
    const int j = cg * 64 + lane;
    const int d0 = dg * 128;
    float acc = 0.f;
#pragma unroll 8
    for (int d = 0; d < 128; ++d)
        acc += hl[d0 + d] * ld1(qW, (size_t)(d0 + d) * ND + j, isf32);
    part[dg][lane] = acc;
    __syncthreads();
    if (dg == 0)
        qo[b * ND + j] = part[0][lane] + part[1][lane] + part[2][lane]
                       + part[3][lane] + ld1(qb, j, isf32);
}

// ============================================================================
// Tail (one block per batch): gate logits -> exact top-256 radix-select ->
// scores (vs precomputed q) -> softmax -> ctx (2-half parallel reduction).
// ============================================================================
__global__ __launch_bounds__(256) void k_tail2(const float* __restrict__ h,
                                               const float* __restrict__ g1,
                                               const float* __restrict__ g2,
                                               const float* __restrict__ qo,
                                               float* __restrict__ ctx)
{
    const int b = blockIdx.x, tid = threadIdx.x;
    const int lane = tid & 63, wv = tid >> 6;
    __shared__ unsigned keys[NT];      // 16 KB
    __shared__ float g2s[NT];          // 16 KB
    __shared__ float qv[ND];
    __shared__ float sc[NSLOTS];
    __shared__ int   sidx[NSLOTS];
    __shared__ float ctxp[2][ND];      // 4 KB
    __shared__ int   red[4];
    __shared__ float fred[4];
    __shared__ int   s_cnt;

    // ---- gate logits -> sortable keys ----
    const float* g2r = g2 + (size_t)b * NT;
    const float* g1r = g1 + (size_t)b * NT;
    for (int i = tid; i < NT; i += 256) g2s[i] = g2r[i];
    qv[tid] = qo[b * ND + tid];
    qv[256 + tid] = qo[b * ND + 256 + tid];
    __syncthreads();
    for (int i = tid; i < NT; i += 256) {
        int cnt = min(NK, NT - 1 - i);
        float s = 0.f;
        for (int j = 1; j <= cnt; ++j) s += g2s[i + j];
        float gate = g1r[i] + ((cnt > 0) ? s / (float)cnt : 0.f);
        unsigned u = __float_as_uint(gate);
        u = (u & 0x80000000u) ? ~u : (u | 0x80000000u);
        keys[i] = u;
    }
    __syncthreads();

    // ---- radix select threshold ----
    unsigned sel = 0;
    for (int bit = 31; bit >= 0; --bit) {
        unsigned cand = sel | (1u << bit);
        int c = 0;
        for (int i = tid; i < NT; i += 256) c += (keys[i] >= cand) ? 1 : 0;
#pragma unroll
        for (int off = 32; off > 0; off >>= 1) c += __shfl_down(c, off, 64);
        if (lane == 0) red[wv] = c;
        __syncthreads();
        int total = red[0] + red[1] + red[2] + red[3];
        __syncthreads();
        if (total >= NSLOTS) sel = cand;
    }
    if (tid == 0) s_cnt = 0;
    __syncthreads();
    for (int i = tid; i < NT; i += 256)
        if (keys[i] > sel) sidx[atomicAdd(&s_cnt, 1)] = i;
    __syncthreads();
    const int base = s_cnt;
    int tc = 0;
    for (int i = tid; i < NT; i += 256) tc += (keys[i] == sel) ? 1 : 0;
#pragma unroll
    for (int off = 32; off > 0; off >>= 1) tc += __shfl_down(tc, off, 64);
    if (lane == 0) red[wv] = tc;
    __syncthreads();
    int tcnt = red[0] + red[1] + red[2] + red[3];
    if (tcnt == NSLOTS - base) {
        for (int i = tid; i < NT; i += 256)
            if (keys[i] == sel) sidx[atomicAdd(&s_cnt, 1)] = i;
    } else if (tid == 0) {   // rare: more ties than slots -> lowest indices
        int p = base;
        for (int i = 0; i < NT && p < NSLOTS; ++i)
            if (keys[i] == sel) sidx[p++] = i;
    }
    __syncthreads();

    // ---- scores + softmax (256 slots <-> 256 threads) ----
    const float* hb = h + (size_t)b * NT * ND;
    float s = 0.f;
    {
        const float* row = hb + (size_t)sidx[tid] * ND;
#pragma unroll 8
        for (int d = 0; d < ND; d += 4) {
            float4 hv = *(const float4*)(row + d);
            float4 qq = *(const float4*)(qv + d);
            s += hv.x * qq.x + hv.y * qq.y + hv.z * qq.z + hv.w * qq.w;
        }
    }
    float mx = s;
#pragma unroll
    for (int off = 32; off > 0; off >>= 1) mx = fmaxf(mx, __shfl_xor(mx, off, 64));
    if (lane == 0) fred[wv] = mx;
    __syncthreads();
    mx = fmaxf(fmaxf(fred[0], fred[1]), fmaxf(fred[2], fred[3]));
    __syncthreads();
    float e = expf(s - mx);
    sc[tid] = e;
    float se = e;
#pragma unroll
    for (int off = 32; off > 0; off >>= 1) se += __shfl_xor(se, off, 64);
    if (lane == 0) fred[wv] = se;
    __syncthreads();
    float inv = 1.f / (fred[0] + fred[1] + fred[2] + fred[3]);

    // ---- ctx: 256 threads = 128 d4-groups x 2 slot-halves ----
    {
        const int half = tid >> 7;
        const int d4 = (tid & 127) * 4;
        const int mbase = half * 128;
        float ax = 0.f, ay = 0.f, az = 0.f, aw = 0.f;
#pragma unroll 8
        for (int mm = 0; mm < 128; ++mm) {
            const float* r = hb + (size_t)sidx[mbase + mm] * ND + d4;
            float4 v = *(const float4*)r;
            float w = sc[mbase + mm];
            ax += w * v.x; ay += w * v.y; az += w * v.z; aw += w * v.w;
        }
        ctxp[half][d4]     = ax;
        ctxp[half][d4 + 1] = ay;
        ctxp[half][d4 + 2] = az;
        ctxp[half][d4 + 3] = aw;
    }
    __syncthreads();
    if (tid < 128) {
        const int d4 = tid * 4;
        float4 o;
        o.x = (ctxp[0][d4]     + ctxp[1][d4])     * inv;
        o.y = (ctxp[0][d4 + 1] + ctxp[1][d4 + 1]) * inv;
        o.z = (ctxp[0][d4 + 2] + ctxp[1][d4 + 2]) * inv;
        o.w = (ctxp[0][d4 + 3] + ctxp[1][d4 + 3]) * inv;
        *(float4*)&ctx[b * ND + d4] = o;
    }
}

// ============================================================================
// out[b][v] = ctx[b] · out_W[:,v] + out_b[v]   (1 col/thread)
// ============================================================================
__global__ __launch_bounds__(256) void k_out(const float* __restrict__ ctx,
                                             const void* __restrict__ outW,
                                             const void* __restrict__ outb,
                                             void* __restrict__ out,
                                             const int* __restrict__ dflag)
{
    const bool isf32 = (*dflag != 0);
    __shared__ float cs[NB * ND];
    const int tid = threadIdx.x;
    for (int i = tid; i < NB * ND; i += 256) cs[i] = ctx[i];
    __syncthreads();
    int v = blockIdx.x * 256 + tid;
    if (v >= NV) return;
    float acc[NB];
#pragma unroll
    for (int bb = 0; bb < NB; ++bb) acc[bb] = 0.f;
#pragma unroll 8
    for (int d = 0; d < ND; ++d) {
        float w = ld1(outW, (size_t)d * NV + v, isf32);
#pragma unroll
        for (int bb = 0; bb < NB; ++bb) acc[bb] += cs[bb * ND + d] * w;
    }
    float ob = ld1(outb, v, isf32);
#pragma unroll
    for (int bb = 0; bb < NB; ++bb) {
        float r = acc[bb] + ob;
        size_t o = (size_t)bb * NV + v;
        if (isf32) ((float*)out)[o] = r;
        else       ((u16*)out)[o]   = f2b(r);
    }
}

// ============================================================================
extern "C" void kernel_launch(void* const* d_in, const int* in_sizes, int n_in,
                              void* d_out, int out_size, void* d_ws, size_t ws_size,
                              hipStream_t stream)
{
    const int*  seq   = (const int*)d_in[0];
    const void* embed = d_in[1];
    const void* W1    = d_in[2];
    const void* b1    = d_in[3];
    const void* W2    = d_in[4];
    const void* b2v   = d_in[5];
    const void* lng   = d_in[6];
    const void* lnb   = d_in[7];
    const void* gateW = d_in[8];
    // d_in[9] = gate_b (constant shift, irrelevant for top-k ordering)
    const void* qW    = d_in[10];
    const void* qb    = d_in[11];
    const void* outW  = d_in[12];
    const void* outb  = d_in[13];

    // ---- ws layout ----
    float* ws   = (float*)d_ws;
    int*   flag = (int*)ws;                    // ws[0..3] (16B pad)
    float* g1   = ws + 4;                      // NM
    float* g2   = g1 + NM;                     // NM
    float* ctx  = g2 + NM;                     // NB*ND
    float* qo   = ctx + NB * ND;               // NB*ND
    float* h    = qo + NB * ND;                // NM*ND f32 (64 MiB)
    u16* ebf    = (u16*)(h + (size_t)NM * ND); // NV*ND bf16 (51.5 MiB)
    u16* W1t    = ebf + (size_t)NV * ND;       // [1024][512] bf16 (1 MiB)
    u16* W2t    = W1t + (size_t)1024 * 512;    // [512][1024] bf16 (1 MiB)
    u16* b1b    = W2t + (size_t)512 * 1024;    // 1024 bf16
    u16* b2b    = b1b + 1024;                  // 512 bf16
    u16* t1     = b2b + 512;                   // [MC][1024] bf16

    // ws-adaptive M-chunk (t1 = MC*2048 B). Host branch on ws_size only.
    const size_t usedB = (size_t)((char*)t1 - (char*)d_ws);
    int MC;
    if      (ws_size >= usedB + (size_t)32768 * 2048) MC = 32768;
    else if (ws_size >= usedB + (size_t)16384 * 2048) MC = 16384;
    else if (ws_size >= usedB + (size_t)8192  * 2048) MC = 8192;
    else                                              MC = 4096;

    k_detect<<<1, 256, 0, stream>>>(W1, flag);
    // pre-convert operands to bf16 (identity copy when input already bf16)
    k_cvt<<<2048, 256, 0, stream>>>(embed, ebf, NV * ND / 8, flag);
    k_cvt<<<1, 256, 0, stream>>>(b1, b1b, 1024 / 8, flag);
    k_cvt<<<1, 256, 0, stream>>>(b2v, b2b, 512 / 8, flag);
    k_cvtWT<<<dim3(32, 16), 256, 0, stream>>>(W1, W1t, 512, 1024, flag);
    k_cvtWT<<<dim3(16, 32), 256, 0, stream>>>(W2, W2t, 1024, 512, flag);

    for (int m0g = 0; m0g < NM; m0g += MC) {
        // GEMM1: t1 = relu(bf16(embed[seq]) @ W1 + b1)    K=512 -> 8 K-steps
        k_bmfma<8, 8, true, true><<<(MC / 128) * 8, 256, 0, stream>>>(
            ebf, seq, W1t, b1b, t1, nullptr, embed, m0g, flag);
        // GEMM2: h = t1 @ W2 + b2 + embed[seq] (residual at original dtype)
        k_bmfma<16, 4, false, false><<<(MC / 128) * 4, 256, 0, stream>>>(
            t1, seq, W2t, b2b, nullptr, h, embed, m0g, flag);
    }

    k_lng<<<NM / 4, 256, 0, stream>>>(h, lng, lnb, gateW, g1, g2, flag);
    k_q<<<64, 256, 0, stream>>>(h, qW, qb, qo, flag);
    k_tail2<<<NB, 256, 0, stream>>>(h, g1, g2, qo, ctx);
    k_out<<<(NV + 255) / 256, 256, 0, stream>>>(ctx, outW, outb, d_out, flag);
}